// Round 11
// baseline (965.900 us; speedup 1.0000x reference)
//
#include <hip/hip_runtime.h>

#define D_IN   2048
#define D_SAE  16384
#define BATCH  4096
#define CAP    256      // max compacted nonzeros per row
#define MAXB   64       // max boundary-band candidates per row
#define DELTA  1e-2f    // band half-width; >= 2x (gemm f16 err + f16 storage err)

typedef __attribute__((ext_vector_type(8))) _Float16 f16x8;
typedef __attribute__((ext_vector_type(4))) _Float16 f16x4;
typedef __attribute__((ext_vector_type(4))) float f32x4;

// ---------------------------------------------------------------------------
// K0: convert f32 -> f16 (RN).
// ---------------------------------------------------------------------------
__global__ __launch_bounds__(256) void to_f16(const float* __restrict__ in,
                                              ushort* __restrict__ out, int n4) {
    int i = blockIdx.x * blockDim.x + threadIdx.x;
    int stride = gridDim.x * blockDim.x;
    for (; i < n4; i += stride) {
        float4 v = ((const float4*)in)[i];
        ushort4 h;
        float*  vp = (float*)&v;
        ushort* hp = (ushort*)&h;
        #pragma unroll
        for (int j = 0; j < 4; ++j) {
            _Float16 f = (_Float16)vp[j];
            hp[j] = *(ushort*)&f;
        }
        ((ushort4*)out)[i] = h;
    }
}

// ---------------------------------------------------------------------------
// K1: raw[b][s] = relu( x·W_enc[s] + b_enc[s] - tau[s] ), f16 MFMA.
// 256x256 tile, 8 waves (2M x 4N), 2 x 64KB double-buffered LDS, K-half
// (BK=32) pipelining with COUNTED vmcnt(8) — never drained to 0 in the main
// loop (T4, m218). 64 sub-iters: {issue 4 stage-loads for (t+1,h);
// vmcnt(8); s_barrier; 12 ds_read_b128; setprio(1); 32 MFMA; setprio(0)}.
//
// LDS layout (chunk-major): [buf][ab][kh][chunk(4)][row(256)][8 f16].
//  - staging one (ab,kh) = contiguous 16KB; wave lane l writes base+l*16
//    (linear dest required by global_load_lds); global source per-lane:
//    panel + row*2048 + koff + chunk*8.
//  - frag ds_read addr = chunk*4096B + row*16B: 64 lanes (4 chunks x 16
//    rows) land on 8 distinct 16B positions mod 128B x 8 lanes each ->
//    uniform over all 32 banks (structural optimum for b128).
//
// Hazard audit (single barrier per sub-iter): issue at (t,h) targets
// buf[(t+1)&1] kh=h, last READ at sub-iter (t-1,h); every wave passed the
// (t,1-h...)/(t,h) barriers since, and ds_read data is consumed (lgkmcnt)
// before a wave reaches its next barrier -> no overwrite race. Loads in
// flight write buf[nbuf] while reads hit buf[cbuf] (disjoint).
// ---------------------------------------------------------------------------
__device__ __forceinline__ void async_copy16(const void* g, void* l) {
    __builtin_amdgcn_global_load_lds(
        (const __attribute__((address_space(1))) unsigned int*)g,
        (__attribute__((address_space(3))) unsigned int*)l, 16, 0, 0);
}

template<int F16OUT>
__global__ __launch_bounds__(512) void gemm_enc_mfma(
        const ushort* __restrict__ xh,    // x_f16 [4096][2048]
        const ushort* __restrict__ wh,    // w_f16 [16384][2048]
        const float* __restrict__ b_enc,
        const float* __restrict__ tau,
        void* __restrict__ rawout) {
    // [buf][ab][kh][chunk][row*8] ushorts = 2*2*2*4*2048*2B = 128 KB
    __shared__ ushort lds[2][2][2][4][2048];

    const int tid  = threadIdx.x;
    const int w    = tid >> 6;         // wave 0..7
    const int lane = tid & 63;
    const int wm   = w >> 2;           // 0..1 (M)
    const int wn   = w & 3;            // 0..3 (N)
    const int m0 = blockIdx.x * 256;
    const int s0 = blockIdx.y * 256;

    const int fr = lane & 15;
    const int fq = lane >> 4;          // 0..3 (k-chunk within k-half)

    // staging: per (ab,kh) 2 issues q; thread covers chunk c=q*2+(tid>>8),
    // row r=tid&255. Per-wave dest is base + lane*16 (linear).
    const int sc   = tid >> 8;         // 0..1
    const int srow = tid & 255;

    const ushort* panelA = xh + (size_t)m0 * 2048;
    const ushort* panelB = wh + (size_t)s0 * 2048;

    auto stage_kh = [&](int bufi, int kh, int koff) {   // koff in f16 units
        #pragma unroll
        for (int q = 0; q < 2; ++q) {
            int c = q * 2 + sc;
            async_copy16(panelA + (size_t)srow * 2048 + koff + c * 8,
                         &lds[bufi][0][kh][c][srow * 8]);
            async_copy16(panelB + (size_t)srow * 2048 + koff + c * 8,
                         &lds[bufi][1][kh][c][srow * 8]);
        }
    };

    f32x4 acc[8][4] = {};

    // prologue: both k-halves of tile 0 into buf 0 (8 loads/thread)
    stage_kh(0, 0, 0);
    stage_kh(0, 1, 32);

#define SUBITER(KH, VM)                                                        \
    do {                                                                       \
        asm volatile("s_waitcnt vmcnt(" #VM ")" ::: "memory");                 \
        asm volatile("s_barrier" ::: "memory");                                \
        f16x8 af[8], bf[4];                                                    \
        _Pragma("unroll") for (int m = 0; m < 8; ++m)                          \
            af[m] = *(const f16x8*)&lds[cbuf][0][KH][fq][(wm * 128 + m * 16 + fr) * 8]; \
        _Pragma("unroll") for (int g = 0; g < 4; ++g)                          \
            bf[g] = *(const f16x8*)&lds[cbuf][1][KH][fq][(wn * 64 + g * 16 + fr) * 8];  \
        __builtin_amdgcn_s_setprio(1);                                         \
        _Pragma("unroll") for (int m = 0; m < 8; ++m)                          \
            _Pragma("unroll") for (int g = 0; g < 4; ++g)                      \
                acc[m][g] = __builtin_amdgcn_mfma_f32_16x16x32_f16(            \
                    af[m], bf[g], acc[m][g], 0, 0, 0);                         \
        __builtin_amdgcn_s_setprio(0);                                         \
    } while (0)

    for (int t = 0; t < 31; ++t) {
        const int cbuf = t & 1, nbuf = cbuf ^ 1;
        const int knext = (t + 1) * 64;
        stage_kh(nbuf, 0, knext);        // 4 loads for (t+1, kh=0)
        SUBITER(0, 8);                   // wait (t,0) done: 8 newer in flight
        stage_kh(nbuf, 1, knext + 32);   // 4 loads for (t+1, kh=1)
        SUBITER(1, 8);                   // wait (t,1) done: 8 newer in flight
    }
    {   // tail tile t=31: nothing left to stage
        const int cbuf = 31 & 1;
        SUBITER(0, 4);                   // only (31,1)'s 4 loads outstanding
        SUBITER(1, 0);
    }
#undef SUBITER

    // epilogue: + b_enc - tau, relu; C/D layout col=fr, row=fq*4+r
    float bias[4];
    int col[4];
    #pragma unroll
    for (int n = 0; n < 4; ++n) {
        col[n] = s0 + wn * 64 + n * 16 + fr;
        bias[n] = b_enc[col[n]] - tau[col[n]];
    }
    #pragma unroll
    for (int m = 0; m < 8; ++m) {
        int rbase = m0 + wm * 128 + m * 16 + fq * 4;
        #pragma unroll
        for (int n = 0; n < 4; ++n) {
            #pragma unroll
            for (int r = 0; r < 4; ++r) {
                float v = fmaxf(acc[m][n][r] + bias[n], 0.f);
                size_t ofs = (size_t)(rbase + r) * D_SAE + col[n];
                if (F16OUT) {
                    _Float16 hv = (_Float16)v;
                    ((ushort*)rawout)[ofs] = *(ushort*)&hv;
                } else {
                    ((float*)rawout)[ofs] = v;
                }
            }
        }
    }
}

// ---------------------------------------------------------------------------
// K2: transpose W_dec (f32 [2048][16384]) -> W_decT (f16 [16384][2048])
// ---------------------------------------------------------------------------
__global__ __launch_bounds__(256) void transpose_wdec_f16(const float* __restrict__ W_dec,
                                                          _Float16* __restrict__ W_decT) {
    __shared__ float t[64][65];
    const int tid = threadIdx.x;
    const int x0 = blockIdx.x * 64;   // feature (s)
    const int y0 = blockIdx.y * 64;   // d_in (i)
    const int tx = tid & 15;
    const int ty = tid >> 4;
    #pragma unroll
    for (int p = 0; p < 4; ++p) {
        float4 v = *(const float4*)&W_dec[(size_t)(y0 + p * 16 + ty) * D_SAE + x0 + tx * 4];
        t[p * 16 + ty][tx * 4 + 0] = v.x;
        t[p * 16 + ty][tx * 4 + 1] = v.y;
        t[p * 16 + ty][tx * 4 + 2] = v.z;
        t[p * 16 + ty][tx * 4 + 3] = v.w;
    }
    __syncthreads();
    #pragma unroll
    for (int p = 0; p < 4; ++p) {
        int s = p * 16 + ty;
        f16x4 o;
        #pragma unroll
        for (int q = 0; q < 4; ++q)
            o[q] = (_Float16)t[tx * 4 + q][s];
        *(f16x4*)&W_decT[(size_t)(x0 + s) * D_IN + y0 + tx * 4] = o;
    }
}

// ---------------------------------------------------------------------------
// K3: exact rank-K select (round-8 verified). Histogram kth localization,
// f64 band refinement, dense nt vector writes. s = i*2048 + tid*8 + j.
// ---------------------------------------------------------------------------
template<int SRC16>
__global__ __launch_bounds__(256) void select_apply(
        const void* __restrict__ rawsrc,
        float* __restrict__ codes, float* __restrict__ mask,
        const int* __restrict__ kptr,
        const float* __restrict__ x, const float* __restrict__ W_enc,
        const float* __restrict__ b_enc, const float* __restrict__ tau,
        int* __restrict__ cnt_out, int* __restrict__ idx_out,
        float* __restrict__ val_out) {
    const int row = blockIdx.x;
    const int tid = threadIdx.x;
    const long base = (long)row * D_SAE;

    float c[8][8];
    if (SRC16) {
        const ushort* rh = (const ushort*)rawsrc;
        #pragma unroll
        for (int i = 0; i < 8; ++i) {
            uint4 u = *(const uint4*)(rh + base + i * 2048 + tid * 8);
            const unsigned* up = (const unsigned*)&u;
            #pragma unroll
            for (int q = 0; q < 4; ++q) {
                ushort b0 = (ushort)(up[q] & 0xFFFFu), b1 = (ushort)(up[q] >> 16);
                _Float16 h0, h1;
                *(ushort*)&h0 = b0; *(ushort*)&h1 = b1;
                c[i][2 * q]     = (float)h0;
                c[i][2 * q + 1] = (float)h1;
            }
        }
    } else {
        const float* rf = (const float*)rawsrc;
        #pragma unroll
        for (int i = 0; i < 8; ++i) {
            float4 v0 = *(const float4*)(rf + base + i * 2048 + tid * 8);
            float4 v1 = *(const float4*)(rf + base + i * 2048 + tid * 8 + 4);
            c[i][0] = v0.x; c[i][1] = v0.y; c[i][2] = v0.z; c[i][3] = v0.w;
            c[i][4] = v1.x; c[i][5] = v1.y; c[i][6] = v1.z; c[i][7] = v1.w;
        }
    }

    int K = kptr[0];
    if (K > D_SAE) K = D_SAE;

    __shared__ int    hist[1024];
    __shared__ int    scan[256];
    __shared__ int    wsum[4];
    __shared__ int    bidx[MAXB];
    __shared__ double exactv[MAXB];
    __shared__ int    selfl[MAXB];
    __shared__ double dsum[4];
    __shared__ int    sh_B, sh_nAB, sh_kpat;

    // --- 1a) histogram of f16-pattern top-10 bits (1024 buckets)
    #pragma unroll
    for (int q = 0; q < 4; ++q) hist[tid + q * 256] = 0;
    if (tid == 0) { sh_B = -1; sh_nAB = 0; }
    __syncthreads();
    #pragma unroll
    for (int i = 0; i < 8; ++i)
        #pragma unroll
        for (int j = 0; j < 8; ++j) {
            _Float16 h = (_Float16)c[i][j];
            ushort pat = *(ushort*)&h;
            if (pat) atomicAdd(&hist[pat >> 6], 1);
        }
    __syncthreads();

    // --- 1b) suffix scan over buckets (thread tid owns buckets 4t..4t+3)
    int s_loc = hist[4 * tid] + hist[4 * tid + 1] + hist[4 * tid + 2] + hist[4 * tid + 3];
    const int my = 255 - tid;
    scan[my] = s_loc;
    __syncthreads();
    #pragma unroll
    for (int off = 1; off < 256; off <<= 1) {
        int a = scan[my];
        int b = (my >= off) ? scan[my - off] : 0;
        __syncthreads();
        scan[my] = a + b;
        __syncthreads();
    }
    int I = scan[my];        // count of elements in buckets >= 4*tid
    int E = I - s_loc;       // count in buckets >= 4*(tid+1)
    if (I >= K && E < K) {   // exactly one thread (when enough positives)
        int cnt = E, b;
        for (b = 4 * tid + 3; b > 4 * tid; --b) {
            cnt += hist[b];
            if (cnt >= K) break;
        }
        if (cnt < K) { cnt += hist[4 * tid]; b = 4 * tid; }
        sh_B = b;
        sh_nAB = cnt - hist[b];    // elements strictly above bucket B
    }
    __syncthreads();
    const int B = sh_B, nAB = sh_nAB;

    // --- 1c) second pass within bucket B (low 6 bits)
    if (tid < 64) hist[tid] = 0;
    __syncthreads();
    if (B >= 0) {
        #pragma unroll
        for (int i = 0; i < 8; ++i)
            #pragma unroll
            for (int j = 0; j < 8; ++j) {
                _Float16 h = (_Float16)c[i][j];
                ushort pat = *(ushort*)&h;
                if (pat && (int)(pat >> 6) == B) atomicAdd(&hist[pat & 63], 1);
            }
    }
    __syncthreads();
    if (tid == 0) {
        int kpat = 0;
        if (B >= 0) {
            int cnt = nAB, l;
            for (l = 63; l >= 0; --l) {
                cnt += hist[l];
                if (cnt >= K) break;
            }
            if (l < 0) l = 0;
            kpat = (B << 6) | l;
        }
        sh_kpat = kpat;
    }
    __syncthreads();
    _Float16 kh; *(ushort*)&kh = (ushort)sh_kpat;
    const float kf = (float)kh;
    const float thr_hi = kf + DELTA;
    const float thr_lo = kf - DELTA;

    // --- 2) count above / collect band
    int cA = 0, cB2 = 0;
    #pragma unroll
    for (int i = 0; i < 8; ++i)
        #pragma unroll
        for (int j = 0; j < 8; ++j) {
            float cc = c[i][j];
            cA  += (cc > thr_hi);
            cB2 += (cc >= thr_lo) && (cc <= thr_hi);
        }
    {
        int a = cA;
        #pragma unroll
        for (int off = 32; off; off >>= 1) a += __shfl_xor(a, off, 64);
        if ((tid & 63) == 0) wsum[tid >> 6] = a;
    }
    __syncthreads();
    const int nA = wsum[0] + wsum[1] + wsum[2] + wsum[3];
    __syncthreads();

    scan[tid] = cB2;
    __syncthreads();
    #pragma unroll
    for (int off = 1; off < 256; off <<= 1) {
        int a = scan[tid];
        int b = (tid >= off) ? scan[tid - off] : 0;
        __syncthreads();
        scan[tid] = a + b;
        __syncthreads();
    }
    int posB = scan[tid] - cB2;
    int nb   = scan[255];
    if (nb > MAXB) nb = MAXB;

    {
        int p = posB;
        #pragma unroll
        for (int i = 0; i < 8; ++i)
            #pragma unroll
            for (int j = 0; j < 8; ++j) {
                float cc = c[i][j];
                if ((cc >= thr_lo) && (cc <= thr_hi)) {
                    if (p < MAXB) bidx[p] = i * 2048 + tid * 8 + j;
                    ++p;
                }
            }
    }
    __syncthreads();

    // --- 3) exact f64 pre for band candidates
    const float* xrow = x + (size_t)row * D_IN;
    for (int jj = 0; jj < nb; ++jj) {
        int s = bidx[jj];
        const float* wrow = W_enc + (size_t)s * D_IN;
        double a = 0.0;
        #pragma unroll
        for (int q = 0; q < 8; ++q)
            a += (double)xrow[tid * 8 + q] * (double)wrow[tid * 8 + q];
        #pragma unroll
        for (int off = 32; off; off >>= 1) a += __shfl_xor(a, off, 64);
        if ((tid & 63) == 0) dsum[tid >> 6] = a;
        __syncthreads();
        if (tid == 0)
            exactv[jj] = dsum[0] + dsum[1] + dsum[2] + dsum[3]
                         + (double)b_enc[s] - (double)tau[s];
        __syncthreads();
    }

    int m = K - nA;
    if (m > nb) m = nb;
    if (tid < nb) {
        double e = exactv[tid];
        int rank = 0;
        for (int l = 0; l < nb; ++l) rank += (exactv[l] > e);
        selfl[tid] = (rank < m) ? 1 : 0;
    }
    __syncthreads();

    // per-thread override bits: owner tid = (s>>3)&255, bit = (s>>11)*8 + (s&7)
    unsigned long long ov = 0ull;
    for (int jj = 0; jj < nb; ++jj) {
        int s = bidx[jj];
        if (((s >> 3) & 255) == tid && selfl[jj])
            ov |= 1ull << (((s >> 11) << 3) | (s & 7));
    }

    // --- 4) final keep predicate, compaction, writes
    int kc = 0;
    #pragma unroll
    for (int i = 0; i < 8; ++i)
        #pragma unroll
        for (int j = 0; j < 8; ++j) {
            float cc = c[i][j];
            bool sel = (cc > thr_hi) || ((ov >> (i * 8 + j)) & 1ull);
            kc += sel && (cc > 0.f);
        }
    __syncthreads();
    scan[tid] = kc;
    __syncthreads();
    #pragma unroll
    for (int off = 1; off < 256; off <<= 1) {
        int a = scan[tid];
        int b = (tid >= off) ? scan[tid - off] : 0;
        __syncthreads();
        scan[tid] = a + b;
        __syncthreads();
    }
    int pos   = scan[tid] - kc;
    int total = scan[255];

    #pragma unroll
    for (int i = 0; i < 8; ++i) {
        f32x4 cf0, cf1, mf0, mf1;
        #pragma unroll
        for (int j = 0; j < 8; ++j) {
            float cc = c[i][j];
            bool sel = (cc > thr_hi) || ((ov >> (i * 8 + j)) & 1ull);
            bool m_  = sel && (cc > 0.f);
            float cv = sel ? cc : 0.f;
            float mv = m_ ? 1.f : 0.f;
            if (j < 4) { cf0[j] = cv; mf0[j] = mv; }
            else       { cf1[j - 4] = cv; mf1[j - 4] = mv; }
            if (m_) {
                if (pos < CAP) {
                    idx_out[row * CAP + pos] = i * 2048 + tid * 8 + j;
                    val_out[row * CAP + pos] = cv;
                }
                ++pos;
            }
        }
        long o = base + i * 2048 + tid * 8;
        __builtin_nontemporal_store(cf0, (f32x4*)(codes + o));
        __builtin_nontemporal_store(cf1, (f32x4*)(codes + o + 4));
        __builtin_nontemporal_store(mf0, (f32x4*)(mask + o));
        __builtin_nontemporal_store(mf1, (f32x4*)(mask + o + 4));
    }
    if (tid == 0) cnt_out[row] = total < CAP ? total : CAP;
}

// ---------------------------------------------------------------------------
// K4: recon[b,:] = sum_j val_j * W_decT16[idx_j, :]   (f16 gather, f32 accum)
// ---------------------------------------------------------------------------
__global__ __launch_bounds__(256) void recon_sparse(const _Float16* __restrict__ Wd16,
                                                    const int* __restrict__ cnt,
                                                    const int* __restrict__ idx,
                                                    const float* __restrict__ val,
                                                    float* __restrict__ recon) {
    const int row = blockIdx.x;
    const int tid = threadIdx.x;
    __shared__ int   s_idx[CAP];
    __shared__ float s_val[CAP];
    const int n = cnt[row];
    for (int j = tid; j < n; j += 256) {
        s_idx[j] = idx[row * CAP + j];
        s_val[j] = val[row * CAP + j];
    }
    __syncthreads();

    float4 a0 = {0.f, 0.f, 0.f, 0.f};
    float4 a1 = {0.f, 0.f, 0.f, 0.f};
    for (int j = 0; j < n; ++j) {
        float c = s_val[j];
        const _Float16* w = Wd16 + (size_t)s_idx[j] * D_IN;
        f16x4 w0 = *(const f16x4*)(w + tid * 4);
        f16x4 w1 = *(const f16x4*)(w + 1024 + tid * 4);
        a0.x = fmaf(c, (float)w0[0], a0.x); a0.y = fmaf(c, (float)w0[1], a0.y);
        a0.z = fmaf(c, (float)w0[2], a0.z); a0.w = fmaf(c, (float)w0[3], a0.w);
        a1.x = fmaf(c, (float)w1[0], a1.x); a1.y = fmaf(c, (float)w1[1], a1.y);
        a1.z = fmaf(c, (float)w1[2], a1.z); a1.w = fmaf(c, (float)w1[3], a1.w);
    }
    float* out = recon + (size_t)row * D_IN;
    *(float4*)(out + tid * 4)        = a0;
    *(float4*)(out + 1024 + tid * 4) = a1;
}

// ---------------------------------------------------------------------------
// Workspace:
//  f16-raw path (needs ~216.3 MB):
//   [0,64M)    w_f16 (phase A) / W_decT f16 (phase B, after select)
//   [64M,80M)  x_f16
//   [80M,208M) raw f16 codes
//   [208M,..)  cnt (16K), idx (4M), val (4M)
//  fallback (ws too small, ~88.3 MB): raw f32 lives in d_out codes region,
//   cnt/idx/val at 80M.
// ---------------------------------------------------------------------------
extern "C" void kernel_launch(void* const* d_in, const int* in_sizes, int n_in,
                              void* d_out, int out_size, void* d_ws, size_t ws_size,
                              hipStream_t stream) {
    const float* x     = (const float*)d_in[0];
    const float* W_enc = (const float*)d_in[1];
    const float* b_enc = (const float*)d_in[2];
    const float* tau   = (const float*)d_in[3];
    const float* W_dec = (const float*)d_in[4];
    const int*   kptr  = (const int*)d_in[5];

    float* recon = (float*)d_out;
    float* codes = recon + (size_t)BATCH * D_IN;
    float* maskp = codes + (size_t)BATCH * D_SAE;

    char* w = (char*)d_ws;
    const size_t OFF_X   = (size_t)D_SAE * D_IN * 2;             // 64M
    const size_t OFF_RAW = OFF_X + (size_t)BATCH * D_IN * 2;     // 80M
    const size_t RAWSZ   = (size_t)BATCH * D_SAE * 2;            // 128M
    const size_t TAILSZ  = 16384 + 2 * (size_t)BATCH * CAP * 4;  // cnt+idx+val
    const bool f16raw = ws_size >= OFF_RAW + RAWSZ + TAILSZ;

    const size_t OFF_CNT = f16raw ? (OFF_RAW + RAWSZ) : OFF_RAW;
    ushort*   w_f16  = (ushort*)w;
    ushort*   x_f16  = (ushort*)(w + OFF_X);
    _Float16* W_decT = (_Float16*)w;                             // phase B
    int*      cnt    = (int*)  (w + OFF_CNT);
    int*      idxl   = (int*)  (w + OFF_CNT + 16384);
    float*    vall   = (float*)(w + OFF_CNT + 16384 + (size_t)BATCH * CAP * 4);
    void*     raw    = f16raw ? (void*)(w + OFF_RAW) : (void*)codes;

    hipLaunchKernelGGL(to_f16, dim3(1024), dim3(256), 0, stream,
                       x, x_f16, BATCH * D_IN / 4);
    hipLaunchKernelGGL(to_f16, dim3(4096), dim3(256), 0, stream,
                       W_enc, w_f16, D_SAE * D_IN / 4);
    if (f16raw) {
        hipLaunchKernelGGL((gemm_enc_mfma<1>), dim3(BATCH / 256, D_SAE / 256), dim3(512), 0, stream,
                           x_f16, w_f16, b_enc, tau, raw);
        hipLaunchKernelGGL((select_apply<1>), dim3(BATCH), dim3(256), 0, stream,
                           raw, codes, maskp, kptr, x, W_enc, b_enc, tau, cnt, idxl, vall);
    } else {
        hipLaunchKernelGGL((gemm_enc_mfma<0>), dim3(BATCH / 256, D_SAE / 256), dim3(512), 0, stream,
                           x_f16, w_f16, b_enc, tau, raw);
        hipLaunchKernelGGL((select_apply<0>), dim3(BATCH), dim3(256), 0, stream,
                           raw, codes, maskp, kptr, x, W_enc, b_enc, tau, cnt, idxl, vall);
    }
    hipLaunchKernelGGL(transpose_wdec_f16, dim3(D_SAE / 64, D_IN / 64), dim3(256), 0, stream,
                       W_dec, W_decT);
    hipLaunchKernelGGL(recon_sparse, dim3(BATCH), dim3(256), 0, stream,
                       W_decT, cnt, idxl, vall, recon);
}

// Round 12
// 700.902 us; speedup vs baseline: 1.3781x; 1.3781x over previous
//
#include <hip/hip_runtime.h>

#define D_IN   2048
#define D_SAE  16384
#define BATCH  4096
#define CAP    256      // max compacted nonzeros per row
#define MAXB   64       // max boundary-band candidates per row
#define DELTA  1e-2f    // band half-width; >= 2x (gemm f16 err + f16 storage err)

typedef __attribute__((ext_vector_type(8))) _Float16 f16x8;
typedef __attribute__((ext_vector_type(4))) _Float16 f16x4;
typedef __attribute__((ext_vector_type(4))) float f32x4;

// ---------------------------------------------------------------------------
// K0: convert f32 -> f16 (RN).
// ---------------------------------------------------------------------------
__global__ __launch_bounds__(256) void to_f16(const float* __restrict__ in,
                                              ushort* __restrict__ out, int n4) {
    int i = blockIdx.x * blockDim.x + threadIdx.x;
    int stride = gridDim.x * blockDim.x;
    for (; i < n4; i += stride) {
        float4 v = ((const float4*)in)[i];
        ushort4 h;
        float*  vp = (float*)&v;
        ushort* hp = (ushort*)&h;
        #pragma unroll
        for (int j = 0; j < 4; ++j) {
            _Float16 f = (_Float16)vp[j];
            hp[j] = *(ushort*)&f;
        }
        ((ushort4*)out)[i] = h;
    }
}

// ---------------------------------------------------------------------------
// K1: raw[b][s] = relu( x·W_enc[s] + b_enc[s] - tau[s] ), f16 MFMA.
// ROUND-8 VERIFIED STRUCTURE (do not touch — 3 structural variants all
// regressed): 256x256 tile, BK=64, 8 waves (2M x 4N), 128 KB double-buffered
// LDS, 4 phases per K-tile {stage 1 half-tile || 12 swizzled ds_read_b128 ->
// s_barrier -> setprio(1) -> 16 MFMA -> setprio(0) -> s_barrier}, one
// vmcnt(0) drain per K-tile boundary. Staging keeps 8 lanes per row = 128B
// contiguous global reads (r11's chunk-major 16B/row scatter was 2x slower).
// LDS bank-conflict-free via chunk rotation (slot = (chunk+row)&7): linear
// global_load_lds dest + inverse-rotated per-lane GLOBAL source + rotated
// ds_read addrs (both-sides-or-neither, rule #21).
// ---------------------------------------------------------------------------
__device__ __forceinline__ void async_copy16(const void* g, void* l) {
    __builtin_amdgcn_global_load_lds(
        (const __attribute__((address_space(1))) unsigned int*)g,
        (__attribute__((address_space(3))) unsigned int*)l, 16, 0, 0);
}

template<int F16OUT>
__global__ __launch_bounds__(512) void gemm_enc_mfma(
        const ushort* __restrict__ xh,    // x_f16 [4096][2048]
        const ushort* __restrict__ wh,    // w_f16 [16384][2048]
        const float* __restrict__ b_enc,
        const float* __restrict__ tau,
        void* __restrict__ rawout) {
    // [buf][A=0/B=1][half][128 rows][8 slots][8 f16] = 128 KB
    __shared__ ushort lds[2][2][2][8192];

    const int tid  = threadIdx.x;
    const int w    = tid >> 6;         // wave 0..7
    const int lane = tid & 63;
    const int wm   = w >> 2;           // 0..1 (M)
    const int wn   = w & 3;            // 0..3 (N)
    const int m0 = blockIdx.x * 256;
    const int s0 = blockIdx.y * 256;

    const int fr = lane & 15;
    const int fq = lane >> 4;          // 0..3

    // staging geometry: issue q stages rows q*64+w*8+(lane>>3), slot lane&7
    const int srow0 = w * 8 + (lane >> 3);     // q=0 row in half (0..63)
    const int srow1 = 64 + srow0;              // q=1 row
    const int sc0i  = (((lane & 7) - srow0) & 7) * 8;  // inverse-rotated chunk

    const ushort* panelA = xh + (size_t)m0 * 2048;
    const ushort* panelB = wh + (size_t)s0 * 2048;

    auto stage_half = [&](int bufi, int ab, int h, int koff) {
        const ushort* gp = (ab == 0) ? panelA : panelB;
        const ushort* g0 = gp + (size_t)(h * 128 + srow0) * 2048 + koff + sc0i;
        const ushort* g1 = gp + (size_t)(h * 128 + srow1) * 2048 + koff + sc0i;
        async_copy16(g0, &lds[bufi][ab][h][w * 512]);
        async_copy16(g1, &lds[bufi][ab][h][4096 + w * 512]);
    };

    // fragment read offsets (ushort units), t-invariant:
    // row r, chunk c=kk*4+fq -> addr = r*64 + ((c+r)&7)*8
    int a_off[8][2], b_off[4][2];
    #pragma unroll
    for (int m = 0; m < 8; ++m) {
        int r = m * 16 + fr;
        #pragma unroll
        for (int kk = 0; kk < 2; ++kk)
            a_off[m][kk] = r * 64 + (((kk * 4 + fq) + r) & 7) * 8;
    }
    #pragma unroll
    for (int g = 0; g < 4; ++g) {
        int r = (wn & 1) * 64 + g * 16 + fr;
        #pragma unroll
        for (int kk = 0; kk < 2; ++kk)
            b_off[g][kk] = r * 64 + (((kk * 4 + fq) + r) & 7) * 8;
    }

    f32x4 acc[8][4] = {};

    // prologue: stage K-tile 0 fully into buf 0
    stage_half(0, 0, 0, 0);
    stage_half(0, 0, 1, 0);
    stage_half(0, 1, 0, 0);
    stage_half(0, 1, 1, 0);
    asm volatile("s_waitcnt vmcnt(0)" ::: "memory");
    asm volatile("s_barrier" ::: "memory");

#define PHASE(QM, QN, AB, H)                                                   \
    do {                                                                       \
        if (t < 31) stage_half(nbuf, AB, H, knext);                            \
        f16x8 af[4][2], bf[2][2];                                              \
        _Pragma("unroll") for (int mm = 0; mm < 4; ++mm)                       \
            _Pragma("unroll") for (int kk = 0; kk < 2; ++kk)                   \
                af[mm][kk] = *(const f16x8*)&ldsA[a_off[(QM) * 4 + mm][kk]];   \
        _Pragma("unroll") for (int nn = 0; nn < 2; ++nn)                       \
            _Pragma("unroll") for (int kk = 0; kk < 2; ++kk)                   \
                bf[nn][kk] = *(const f16x8*)&ldsB[b_off[(QN) * 2 + nn][kk]];   \
        asm volatile("s_barrier" ::: "memory");                                \
        __builtin_amdgcn_s_setprio(1);                                         \
        _Pragma("unroll") for (int kk = 0; kk < 2; ++kk)                       \
            _Pragma("unroll") for (int mm = 0; mm < 4; ++mm)                   \
                _Pragma("unroll") for (int nn = 0; nn < 2; ++nn)               \
                    acc[(QM) * 4 + mm][(QN) * 2 + nn] =                        \
                        __builtin_amdgcn_mfma_f32_16x16x32_f16(                \
                            af[mm][kk], bf[nn][kk],                            \
                            acc[(QM) * 4 + mm][(QN) * 2 + nn], 0, 0, 0);       \
        __builtin_amdgcn_s_setprio(0);                                         \
        asm volatile("s_barrier" ::: "memory");                                \
    } while (0)

    for (int t = 0; t < 32; ++t) {
        const int cbuf = t & 1, nbuf = cbuf ^ 1;
        const int knext = (t + 1) * 64;
        const ushort* ldsA = &lds[cbuf][0][wm][0];
        const ushort* ldsB = &lds[cbuf][1][wn >> 1][0];
        PHASE(0, 0, 0, 0);
        PHASE(0, 1, 0, 1);
        PHASE(1, 0, 1, 0);
        PHASE(1, 1, 1, 1);
        asm volatile("s_waitcnt vmcnt(0)" ::: "memory");
        asm volatile("s_barrier" ::: "memory");
    }
#undef PHASE

    // epilogue: + b_enc - tau, relu; C/D layout col=fr, row=fq*4+r
    float bias[4];
    int col[4];
    #pragma unroll
    for (int n = 0; n < 4; ++n) {
        col[n] = s0 + wn * 64 + n * 16 + fr;
        bias[n] = b_enc[col[n]] - tau[col[n]];
    }
    #pragma unroll
    for (int m = 0; m < 8; ++m) {
        int rbase = m0 + wm * 128 + m * 16 + fq * 4;
        #pragma unroll
        for (int n = 0; n < 4; ++n) {
            #pragma unroll
            for (int r = 0; r < 4; ++r) {
                float v = fmaxf(acc[m][n][r] + bias[n], 0.f);
                size_t ofs = (size_t)(rbase + r) * D_SAE + col[n];
                if (F16OUT) {
                    _Float16 hv = (_Float16)v;
                    ((ushort*)rawout)[ofs] = *(ushort*)&hv;
                } else {
                    ((float*)rawout)[ofs] = v;
                }
            }
        }
    }
}

// ---------------------------------------------------------------------------
// K2: transpose W_dec (f32 [2048][16384]) -> W_decT (f16 [16384][2048])
// ---------------------------------------------------------------------------
__global__ __launch_bounds__(256) void transpose_wdec_f16(const float* __restrict__ W_dec,
                                                          _Float16* __restrict__ W_decT) {
    __shared__ float t[64][65];
    const int tid = threadIdx.x;
    const int x0 = blockIdx.x * 64;   // feature (s)
    const int y0 = blockIdx.y * 64;   // d_in (i)
    const int tx = tid & 15;
    const int ty = tid >> 4;
    #pragma unroll
    for (int p = 0; p < 4; ++p) {
        float4 v = *(const float4*)&W_dec[(size_t)(y0 + p * 16 + ty) * D_SAE + x0 + tx * 4];
        t[p * 16 + ty][tx * 4 + 0] = v.x;
        t[p * 16 + ty][tx * 4 + 1] = v.y;
        t[p * 16 + ty][tx * 4 + 2] = v.z;
        t[p * 16 + ty][tx * 4 + 3] = v.w;
    }
    __syncthreads();
    #pragma unroll
    for (int p = 0; p < 4; ++p) {
        int s = p * 16 + ty;
        f16x4 o;
        #pragma unroll
        for (int q = 0; q < 4; ++q)
            o[q] = (_Float16)t[tx * 4 + q][s];
        *(f16x4*)&W_decT[(size_t)(x0 + s) * D_IN + y0 + tx * 4] = o;
    }
}

// ---------------------------------------------------------------------------
// K3: exact rank-K select (round-8 verified, untouched). Histogram kth
// localization, f64 band refinement, dense nt vector writes.
// s = i*2048 + tid*8 + j.
// ---------------------------------------------------------------------------
template<int SRC16>
__global__ __launch_bounds__(256) void select_apply(
        const void* __restrict__ rawsrc,
        float* __restrict__ codes, float* __restrict__ mask,
        const int* __restrict__ kptr,
        const float* __restrict__ x, const float* __restrict__ W_enc,
        const float* __restrict__ b_enc, const float* __restrict__ tau,
        int* __restrict__ cnt_out, int* __restrict__ idx_out,
        float* __restrict__ val_out) {
    const int row = blockIdx.x;
    const int tid = threadIdx.x;
    const long base = (long)row * D_SAE;

    float c[8][8];
    if (SRC16) {
        const ushort* rh = (const ushort*)rawsrc;
        #pragma unroll
        for (int i = 0; i < 8; ++i) {
            uint4 u = *(const uint4*)(rh + base + i * 2048 + tid * 8);
            const unsigned* up = (const unsigned*)&u;
            #pragma unroll
            for (int q = 0; q < 4; ++q) {
                ushort b0 = (ushort)(up[q] & 0xFFFFu), b1 = (ushort)(up[q] >> 16);
                _Float16 h0, h1;
                *(ushort*)&h0 = b0; *(ushort*)&h1 = b1;
                c[i][2 * q]     = (float)h0;
                c[i][2 * q + 1] = (float)h1;
            }
        }
    } else {
        const float* rf = (const float*)rawsrc;
        #pragma unroll
        for (int i = 0; i < 8; ++i) {
            float4 v0 = *(const float4*)(rf + base + i * 2048 + tid * 8);
            float4 v1 = *(const float4*)(rf + base + i * 2048 + tid * 8 + 4);
            c[i][0] = v0.x; c[i][1] = v0.y; c[i][2] = v0.z; c[i][3] = v0.w;
            c[i][4] = v1.x; c[i][5] = v1.y; c[i][6] = v1.z; c[i][7] = v1.w;
        }
    }

    int K = kptr[0];
    if (K > D_SAE) K = D_SAE;

    __shared__ int    hist[1024];
    __shared__ int    scan[256];
    __shared__ int    wsum[4];
    __shared__ int    bidx[MAXB];
    __shared__ double exactv[MAXB];
    __shared__ int    selfl[MAXB];
    __shared__ double dsum[4];
    __shared__ int    sh_B, sh_nAB, sh_kpat;

    // --- 1a) histogram of f16-pattern top-10 bits (1024 buckets)
    #pragma unroll
    for (int q = 0; q < 4; ++q) hist[tid + q * 256] = 0;
    if (tid == 0) { sh_B = -1; sh_nAB = 0; }
    __syncthreads();
    #pragma unroll
    for (int i = 0; i < 8; ++i)
        #pragma unroll
        for (int j = 0; j < 8; ++j) {
            _Float16 h = (_Float16)c[i][j];
            ushort pat = *(ushort*)&h;
            if (pat) atomicAdd(&hist[pat >> 6], 1);
        }
    __syncthreads();

    // --- 1b) suffix scan over buckets (thread tid owns buckets 4t..4t+3)
    int s_loc = hist[4 * tid] + hist[4 * tid + 1] + hist[4 * tid + 2] + hist[4 * tid + 3];
    const int my = 255 - tid;
    scan[my] = s_loc;
    __syncthreads();
    #pragma unroll
    for (int off = 1; off < 256; off <<= 1) {
        int a = scan[my];
        int b = (my >= off) ? scan[my - off] : 0;
        __syncthreads();
        scan[my] = a + b;
        __syncthreads();
    }
    int I = scan[my];        // count of elements in buckets >= 4*tid
    int E = I - s_loc;       // count in buckets >= 4*(tid+1)
    if (I >= K && E < K) {   // exactly one thread (when enough positives)
        int cnt = E, b;
        for (b = 4 * tid + 3; b > 4 * tid; --b) {
            cnt += hist[b];
            if (cnt >= K) break;
        }
        if (cnt < K) { cnt += hist[4 * tid]; b = 4 * tid; }
        sh_B = b;
        sh_nAB = cnt - hist[b];    // elements strictly above bucket B
    }
    __syncthreads();
    const int B = sh_B, nAB = sh_nAB;

    // --- 1c) second pass within bucket B (low 6 bits)
    if (tid < 64) hist[tid] = 0;
    __syncthreads();
    if (B >= 0) {
        #pragma unroll
        for (int i = 0; i < 8; ++i)
            #pragma unroll
            for (int j = 0; j < 8; ++j) {
                _Float16 h = (_Float16)c[i][j];
                ushort pat = *(ushort*)&h;
                if (pat && (int)(pat >> 6) == B) atomicAdd(&hist[pat & 63], 1);
            }
    }
    __syncthreads();
    if (tid == 0) {
        int kpat = 0;
        if (B >= 0) {
            int cnt = nAB, l;
            for (l = 63; l >= 0; --l) {
                cnt += hist[l];
                if (cnt >= K) break;
            }
            if (l < 0) l = 0;
            kpat = (B << 6) | l;
        }
        sh_kpat = kpat;
    }
    __syncthreads();
    _Float16 kh; *(ushort*)&kh = (ushort)sh_kpat;
    const float kf = (float)kh;
    const float thr_hi = kf + DELTA;
    const float thr_lo = kf - DELTA;

    // --- 2) count above / collect band
    int cA = 0, cB2 = 0;
    #pragma unroll
    for (int i = 0; i < 8; ++i)
        #pragma unroll
        for (int j = 0; j < 8; ++j) {
            float cc = c[i][j];
            cA  += (cc > thr_hi);
            cB2 += (cc >= thr_lo) && (cc <= thr_hi);
        }
    {
        int a = cA;
        #pragma unroll
        for (int off = 32; off; off >>= 1) a += __shfl_xor(a, off, 64);
        if ((tid & 63) == 0) wsum[tid >> 6] = a;
    }
    __syncthreads();
    const int nA = wsum[0] + wsum[1] + wsum[2] + wsum[3];
    __syncthreads();

    scan[tid] = cB2;
    __syncthreads();
    #pragma unroll
    for (int off = 1; off < 256; off <<= 1) {
        int a = scan[tid];
        int b = (tid >= off) ? scan[tid - off] : 0;
        __syncthreads();
        scan[tid] = a + b;
        __syncthreads();
    }
    int posB = scan[tid] - cB2;
    int nb   = scan[255];
    if (nb > MAXB) nb = MAXB;

    {
        int p = posB;
        #pragma unroll
        for (int i = 0; i < 8; ++i)
            #pragma unroll
            for (int j = 0; j < 8; ++j) {
                float cc = c[i][j];
                if ((cc >= thr_lo) && (cc <= thr_hi)) {
                    if (p < MAXB) bidx[p] = i * 2048 + tid * 8 + j;
                    ++p;
                }
            }
    }
    __syncthreads();

    // --- 3) exact f64 pre for band candidates
    const float* xrow = x + (size_t)row * D_IN;
    for (int jj = 0; jj < nb; ++jj) {
        int s = bidx[jj];
        const float* wrow = W_enc + (size_t)s * D_IN;
        double a = 0.0;
        #pragma unroll
        for (int q = 0; q < 8; ++q)
            a += (double)xrow[tid * 8 + q] * (double)wrow[tid * 8 + q];
        #pragma unroll
        for (int off = 32; off; off >>= 1) a += __shfl_xor(a, off, 64);
        if ((tid & 63) == 0) dsum[tid >> 6] = a;
        __syncthreads();
        if (tid == 0)
            exactv[jj] = dsum[0] + dsum[1] + dsum[2] + dsum[3]
                         + (double)b_enc[s] - (double)tau[s];
        __syncthreads();
    }

    int m = K - nA;
    if (m > nb) m = nb;
    if (tid < nb) {
        double e = exactv[tid];
        int rank = 0;
        for (int l = 0; l < nb; ++l) rank += (exactv[l] > e);
        selfl[tid] = (rank < m) ? 1 : 0;
    }
    __syncthreads();

    // per-thread override bits: owner tid = (s>>3)&255, bit = (s>>11)*8 + (s&7)
    unsigned long long ov = 0ull;
    for (int jj = 0; jj < nb; ++jj) {
        int s = bidx[jj];
        if (((s >> 3) & 255) == tid && selfl[jj])
            ov |= 1ull << (((s >> 11) << 3) | (s & 7));
    }

    // --- 4) final keep predicate, compaction, writes
    int kc = 0;
    #pragma unroll
    for (int i = 0; i < 8; ++i)
        #pragma unroll
        for (int j = 0; j < 8; ++j) {
            float cc = c[i][j];
            bool sel = (cc > thr_hi) || ((ov >> (i * 8 + j)) & 1ull);
            kc += sel && (cc > 0.f);
        }
    __syncthreads();
    scan[tid] = kc;
    __syncthreads();
    #pragma unroll
    for (int off = 1; off < 256; off <<= 1) {
        int a = scan[tid];
        int b = (tid >= off) ? scan[tid - off] : 0;
        __syncthreads();
        scan[tid] = a + b;
        __syncthreads();
    }
    int pos   = scan[tid] - kc;
    int total = scan[255];

    #pragma unroll
    for (int i = 0; i < 8; ++i) {
        f32x4 cf0, cf1, mf0, mf1;
        #pragma unroll
        for (int j = 0; j < 8; ++j) {
            float cc = c[i][j];
            bool sel = (cc > thr_hi) || ((ov >> (i * 8 + j)) & 1ull);
            bool m_  = sel && (cc > 0.f);
            float cv = sel ? cc : 0.f;
            float mv = m_ ? 1.f : 0.f;
            if (j < 4) { cf0[j] = cv; mf0[j] = mv; }
            else       { cf1[j - 4] = cv; mf1[j - 4] = mv; }
            if (m_) {
                if (pos < CAP) {
                    idx_out[row * CAP + pos] = i * 2048 + tid * 8 + j;
                    val_out[row * CAP + pos] = cv;
                }
                ++pos;
            }
        }
        long o = base + i * 2048 + tid * 8;
        __builtin_nontemporal_store(cf0, (f32x4*)(codes + o));
        __builtin_nontemporal_store(cf1, (f32x4*)(codes + o + 4));
        __builtin_nontemporal_store(mf0, (f32x4*)(mask + o));
        __builtin_nontemporal_store(mf1, (f32x4*)(mask + o + 4));
    }
    if (tid == 0) cnt_out[row] = total < CAP ? total : CAP;
}

// ---------------------------------------------------------------------------
// K4: recon[b,:] = sum_j val_j * W_decT16[idx_j, :]   (f16 gather, f32 accum)
// COLUMN-SPLIT: 2 blocks per row, each owns 1024 of 2048 columns. Per output
// element the summation order is unchanged (bit-identical to round 8) —
// only the work distribution changes. Doubles blocks/CU for latency hiding,
// halves per-block gather volume.
// ---------------------------------------------------------------------------
__global__ __launch_bounds__(256) void recon_sparse(const _Float16* __restrict__ Wd16,
                                                    const int* __restrict__ cnt,
                                                    const int* __restrict__ idx,
                                                    const float* __restrict__ val,
                                                    float* __restrict__ recon) {
    const int row  = blockIdx.x >> 1;
    const int half = blockIdx.x & 1;   // column half: [half*1024, half*1024+1024)
    const int tid  = threadIdx.x;
    __shared__ int   s_idx[CAP];
    __shared__ float s_val[CAP];
    const int n = cnt[row];
    for (int j = tid; j < n; j += 256) {
        s_idx[j] = idx[row * CAP + j];
        s_val[j] = val[row * CAP + j];
    }
    __syncthreads();

    const int colb = half * 1024 + tid * 4;
    float4 a = {0.f, 0.f, 0.f, 0.f};
    for (int j = 0; j < n; ++j) {
        float c = s_val[j];
        f16x4 w0 = *(const f16x4*)(Wd16 + (size_t)s_idx[j] * D_IN + colb);
        a.x = fmaf(c, (float)w0[0], a.x); a.y = fmaf(c, (float)w0[1], a.y);
        a.z = fmaf(c, (float)w0[2], a.z); a.w = fmaf(c, (float)w0[3], a.w);
    }
    *(float4*)(recon + (size_t)row * D_IN + colb) = a;
}

// ---------------------------------------------------------------------------
// Workspace:
//  f16-raw path (needs ~216.3 MB):
//   [0,64M)    w_f16 (phase A) / W_decT f16 (phase B, after select)
//   [64M,80M)  x_f16
//   [80M,208M) raw f16 codes
//   [208M,..)  cnt (16K), idx (4M), val (4M)
//  fallback (ws too small, ~88.3 MB): raw f32 lives in d_out codes region,
//   cnt/idx/val at 80M.
// ---------------------------------------------------------------------------
extern "C" void kernel_launch(void* const* d_in, const int* in_sizes, int n_in,
                              void* d_out, int out_size, void* d_ws, size_t ws_size,
                              hipStream_t stream) {
    const float* x     = (const float*)d_in[0];
    const float* W_enc = (const float*)d_in[1];
    const float* b_enc = (const float*)d_in[2];
    const float* tau   = (const float*)d_in[3];
    const float* W_dec = (const float*)d_in[4];
    const int*   kptr  = (const int*)d_in[5];

    float* recon = (float*)d_out;
    float* codes = recon + (size_t)BATCH * D_IN;
    float* maskp = codes + (size_t)BATCH * D_SAE;

    char* w = (char*)d_ws;
    const size_t OFF_X   = (size_t)D_SAE * D_IN * 2;             // 64M
    const size_t OFF_RAW = OFF_X + (size_t)BATCH * D_IN * 2;     // 80M
    const size_t RAWSZ   = (size_t)BATCH * D_SAE * 2;            // 128M
    const size_t TAILSZ  = 16384 + 2 * (size_t)BATCH * CAP * 4;  // cnt+idx+val
    const bool f16raw = ws_size >= OFF_RAW + RAWSZ + TAILSZ;

    const size_t OFF_CNT = f16raw ? (OFF_RAW + RAWSZ) : OFF_RAW;
    ushort*   w_f16  = (ushort*)w;
    ushort*   x_f16  = (ushort*)(w + OFF_X);
    _Float16* W_decT = (_Float16*)w;                             // phase B
    int*      cnt    = (int*)  (w + OFF_CNT);
    int*      idxl   = (int*)  (w + OFF_CNT + 16384);
    float*    vall   = (float*)(w + OFF_CNT + 16384 + (size_t)BATCH * CAP * 4);
    void*     raw    = f16raw ? (void*)(w + OFF_RAW) : (void*)codes;

    hipLaunchKernelGGL(to_f16, dim3(1024), dim3(256), 0, stream,
                       x, x_f16, BATCH * D_IN / 4);
    hipLaunchKernelGGL(to_f16, dim3(4096), dim3(256), 0, stream,
                       W_enc, w_f16, D_SAE * D_IN / 4);
    if (f16raw) {
        hipLaunchKernelGGL((gemm_enc_mfma<1>), dim3(BATCH / 256, D_SAE / 256), dim3(512), 0, stream,
                           x_f16, w_f16, b_enc, tau, raw);
        hipLaunchKernelGGL((select_apply<1>), dim3(BATCH), dim3(256), 0, stream,
                           raw, codes, maskp, kptr, x, W_enc, b_enc, tau, cnt, idxl, vall);
    } else {
        hipLaunchKernelGGL((gemm_enc_mfma<0>), dim3(BATCH / 256, D_SAE / 256), dim3(512), 0, stream,
                           x_f16, w_f16, b_enc, tau, raw);
        hipLaunchKernelGGL((select_apply<0>), dim3(BATCH), dim3(256), 0, stream,
                           raw, codes, maskp, kptr, x, W_enc, b_enc, tau, cnt, idxl, vall);
    }
    hipLaunchKernelGGL(transpose_wdec_f16, dim3(D_SAE / 64, D_IN / 64), dim3(256), 0, stream,
                       W_dec, W_decT);
    hipLaunchKernelGGL(recon_sparse, dim3(BATCH * 2), dim3(256), 0, stream,
                       W_decT, cnt, idxl, vall, recon);
}

// Round 14
// 700.056 us; speedup vs baseline: 1.3797x; 1.0012x over previous
//
#include <hip/hip_runtime.h>

#define D_IN   2048
#define D_SAE  16384
#define BATCH  4096
#define CAP    256      // max compacted nonzeros per row
#define MAXB   64       // max boundary-band candidates per row
#define DELTA  1e-2f    // band half-width; >= 2x (gemm f16 err + f16 storage err)

typedef __attribute__((ext_vector_type(8))) _Float16 f16x8;
typedef __attribute__((ext_vector_type(4))) _Float16 f16x4;
typedef __attribute__((ext_vector_type(4))) float f32x4;

// ---------------------------------------------------------------------------
// K0: convert f32 -> f16 (RN).
// ---------------------------------------------------------------------------
__global__ __launch_bounds__(256) void to_f16(const float* __restrict__ in,
                                              ushort* __restrict__ out, int n4) {
    int i = blockIdx.x * blockDim.x + threadIdx.x;
    int stride = gridDim.x * blockDim.x;
    for (; i < n4; i += stride) {
        float4 v = ((const float4*)in)[i];
        ushort4 h;
        float*  vp = (float*)&v;
        ushort* hp = (ushort*)&h;
        #pragma unroll
        for (int j = 0; j < 4; ++j) {
            _Float16 f = (_Float16)vp[j];
            hp[j] = *(ushort*)&f;
        }
        ((ushort4*)out)[i] = h;
    }
}

// ---------------------------------------------------------------------------
// K1: raw[b][s] = relu( x·W_enc[s] + b_enc[s] - tau[s] ), f16 MFMA.
// 256x256 tile, BK=64, 8 waves (2M x 4N). 9-slot LDS RING (144 KB), depth-5
// prefetch, COUNTED vmcnt(4) once per tile (T4, m218).
//
// r13 POST-MORTEM: 8-slot/depth-6 overwrote unit u-8 = 4t+p-2, which for
// p=2,3 is the CURRENT tile's A0/B0 (still being read) -> race, absmax 3.7.
// Fix: 9 slots so overwrite target u-9 = 4t+p-4 is ALWAYS in tile t-1
// (last read at (t-1,3), consumed before its trailing barrier; the stage
// issue at (t,p) is >=1 barrier later for every p). Slots of in-flight
// units (4t+5..4t+8 mod 9) are disjoint from current-tile slots
// (4t..4t+3 mod 9) and from the pre-staged 4t+4.
//
// Units: u = 4*tile + ui; ui: 0=A0(ab0,h0) 1=B0(ab1,h0) 2=B1(ab1,h1)
// 3=A1(ab0,h1); slot = u % 9; staged at phase-start p of tile t for
// u = 4t+p+5 (prologue pre-stages u=0..4). Wave (wm,wn) reads only units
// A[wm] (0 or 3) and B[1+(wn>>1)] each phase; vmcnt(4) at phase 0 allows
// only the 2 newest units outstanding -> units 4t..4t+3 landed, youngest
// needed (4t+3) staged 2 phases earlier (~500-800 cyc cover vs r8's 1).
// Tail: last unit 127 staged at (30,2); t=31 waits vmcnt(0).
// Staging geometry + chunk-rotation swizzle byte-identical to round-8
// (8 lanes/row = 128B coalesced; linear global_load_lds dest +
// inverse-rotated global source + rotated ds_read, rule #21).
// ---------------------------------------------------------------------------
__device__ __forceinline__ void async_copy16(const void* g, void* l) {
    __builtin_amdgcn_global_load_lds(
        (const __attribute__((address_space(1))) unsigned int*)g,
        (__attribute__((address_space(3))) unsigned int*)l, 16, 0, 0);
}

template<int F16OUT>
__global__ __launch_bounds__(512) void gemm_enc_mfma(
        const ushort* __restrict__ xh,    // x_f16 [4096][2048]
        const ushort* __restrict__ wh,    // w_f16 [16384][2048]
        const float* __restrict__ b_enc,
        const float* __restrict__ tau,
        void* __restrict__ rawout) {
    __shared__ ushort lds9[9][8192];   // 9 ring slots x 16 KB = 144 KB

    const int tid  = threadIdx.x;
    const int w    = tid >> 6;         // wave 0..7
    const int lane = tid & 63;
    const int wm   = w >> 2;           // 0..1 (M)
    const int wn   = w & 3;            // 0..3 (N)
    const int m0 = blockIdx.x * 256;
    const int s0 = blockIdx.y * 256;

    const int fr = lane & 15;
    const int fq = lane >> 4;          // 0..3

    // staging geometry (r8-verified): 8 lanes/row, 128B contiguous per row
    const int srow0 = w * 8 + (lane >> 3);     // row in half (0..63)
    const int srow1 = 64 + srow0;
    const int sc0i  = (((lane & 7) - srow0) & 7) * 8;  // inverse-rotated chunk

    const ushort* panelA = xh + (size_t)m0 * 2048;
    const ushort* panelB = wh + (size_t)s0 * 2048;

    auto stage_unit = [&](int slot, int ab, int h, int koff) {
        const ushort* gp = (ab == 0) ? panelA : panelB;
        const ushort* g0 = gp + (size_t)(h * 128 + srow0) * 2048 + koff + sc0i;
        const ushort* g1 = gp + (size_t)(h * 128 + srow1) * 2048 + koff + sc0i;
        async_copy16(g0, &lds9[slot][w * 512]);
        async_copy16(g1, &lds9[slot][4096 + w * 512]);
    };

    // fragment read offsets within a slot (ushort units), t-invariant:
    // row r, chunk c=kk*4+fq -> addr = r*64 + ((c+r)&7)*8 (rotation swizzle)
    int a_off[8][2], b_off[4][2];
    #pragma unroll
    for (int m = 0; m < 8; ++m) {
        int r = m * 16 + fr;
        #pragma unroll
        for (int kk = 0; kk < 2; ++kk)
            a_off[m][kk] = r * 64 + (((kk * 4 + fq) + r) & 7) * 8;
    }
    #pragma unroll
    for (int g = 0; g < 4; ++g) {
        int r = (wn & 1) * 64 + g * 16 + fr;
        #pragma unroll
        for (int kk = 0; kk < 2; ++kk)
            b_off[g][kk] = r * 64 + (((kk * 4 + fq) + r) & 7) * 8;
    }

    f32x4 acc[8][4] = {};

    // prologue: pre-stage units u=0..4 (tile 0 complete + A0 of tile 1)
    stage_unit(0, 0, 0, 0);
    stage_unit(1, 1, 0, 0);
    stage_unit(2, 1, 1, 0);
    stage_unit(3, 0, 1, 0);
    stage_unit(4, 0, 0, 64);

    const int wmu = wm ? 3 : 0;        // wave's A unit-in-tile
    const int wbu = 1 + (wn >> 1);     // wave's B unit-in-tile

// stage the unit due at phase P of tile t (u = 4t+P+5), guarded past the end
#define STG(P)                                                                 \
    do {                                                                       \
        int u_ = 4 * t + (P) + 5;                                              \
        if (u_ < 128) {                                                        \
            int ui_ = u_ & 3;                                                  \
            stage_unit(u_ % 9, (ui_ == 0 || ui_ == 3) ? 0 : 1,                 \
                       (ui_ >= 2) ? 1 : 0, (u_ >> 2) * 64);                    \
        }                                                                      \
    } while (0)

#define PHASE(QM, QN, P)                                                       \
    do {                                                                       \
        STG(P);                                                                \
        if ((P) == 0) {                                                        \
            if (t != 31) asm volatile("s_waitcnt vmcnt(4)" ::: "memory");      \
            else         asm volatile("s_waitcnt vmcnt(0)" ::: "memory");      \
        }                                                                      \
        asm volatile("s_barrier" ::: "memory");                                \
        f16x8 af[4][2], bf[2][2];                                              \
        _Pragma("unroll") for (int mm = 0; mm < 4; ++mm)                       \
            _Pragma("unroll") for (int kk = 0; kk < 2; ++kk)                   \
                af[mm][kk] = *(const f16x8*)&ldsA[a_off[(QM) * 4 + mm][kk]];   \
        _Pragma("unroll") for (int nn = 0; nn < 2; ++nn)                       \
            _Pragma("unroll") for (int kk = 0; kk < 2; ++kk)                   \
                bf[nn][kk] = *(const f16x8*)&ldsB[b_off[(QN) * 2 + nn][kk]];   \
        __builtin_amdgcn_s_setprio(1);                                         \
        _Pragma("unroll") for (int kk = 0; kk < 2; ++kk)                       \
            _Pragma("unroll") for (int mm = 0; mm < 4; ++mm)                   \
                _Pragma("unroll") for (int nn = 0; nn < 2; ++nn)               \
                    acc[(QM) * 4 + mm][(QN) * 2 + nn] =                        \
                        __builtin_amdgcn_mfma_f32_16x16x32_f16(                \
                            af[mm][kk], bf[nn][kk],                            \
                            acc[(QM) * 4 + mm][(QN) * 2 + nn], 0, 0, 0);       \
        __builtin_amdgcn_s_setprio(0);                                         \
        asm volatile("s_barrier" ::: "memory");                                \
    } while (0)

    for (int t = 0; t < 32; ++t) {
        const ushort* ldsA = &lds9[(4 * t + wmu) % 9][0];
        const ushort* ldsB = &lds9[(4 * t + wbu) % 9][0];
        PHASE(0, 0, 0);
        PHASE(0, 1, 1);
        PHASE(1, 0, 2);
        PHASE(1, 1, 3);
    }
#undef PHASE
#undef STG

    // epilogue: + b_enc - tau, relu; C/D layout col=fr, row=fq*4+r
    float bias[4];
    int col[4];
    #pragma unroll
    for (int n = 0; n < 4; ++n) {
        col[n] = s0 + wn * 64 + n * 16 + fr;
        bias[n] = b_enc[col[n]] - tau[col[n]];
    }
    #pragma unroll
    for (int m = 0; m < 8; ++m) {
        int rbase = m0 + wm * 128 + m * 16 + fq * 4;
        #pragma unroll
        for (int n = 0; n < 4; ++n) {
            #pragma unroll
            for (int r = 0; r < 4; ++r) {
                float v = fmaxf(acc[m][n][r] + bias[n], 0.f);
                size_t ofs = (size_t)(rbase + r) * D_SAE + col[n];
                if (F16OUT) {
                    _Float16 hv = (_Float16)v;
                    ((ushort*)rawout)[ofs] = *(ushort*)&hv;
                } else {
                    ((float*)rawout)[ofs] = v;
                }
            }
        }
    }
}

// ---------------------------------------------------------------------------
// K2: transpose W_dec (f32 [2048][16384]) -> W_decT (f16 [16384][2048])
// ---------------------------------------------------------------------------
__global__ __launch_bounds__(256) void transpose_wdec_f16(const float* __restrict__ W_dec,
                                                          _Float16* __restrict__ W_decT) {
    __shared__ float t[64][65];
    const int tid = threadIdx.x;
    const int x0 = blockIdx.x * 64;   // feature (s)
    const int y0 = blockIdx.y * 64;   // d_in (i)
    const int tx = tid & 15;
    const int ty = tid >> 4;
    #pragma unroll
    for (int p = 0; p < 4; ++p) {
        float4 v = *(const float4*)&W_dec[(size_t)(y0 + p * 16 + ty) * D_SAE + x0 + tx * 4];
        t[p * 16 + ty][tx * 4 + 0] = v.x;
        t[p * 16 + ty][tx * 4 + 1] = v.y;
        t[p * 16 + ty][tx * 4 + 2] = v.z;
        t[p * 16 + ty][tx * 4 + 3] = v.w;
    }
    __syncthreads();
    #pragma unroll
    for (int p = 0; p < 4; ++p) {
        int s = p * 16 + ty;
        f16x4 o;
        #pragma unroll
        for (int q = 0; q < 4; ++q)
            o[q] = (_Float16)t[tx * 4 + q][s];
        *(f16x4*)&W_decT[(size_t)(x0 + s) * D_IN + y0 + tx * 4] = o;
    }
}

// ---------------------------------------------------------------------------
// K3: exact rank-K select (round-8 verified, untouched). Histogram kth
// localization, f64 band refinement, dense nt vector writes.
// s = i*2048 + tid*8 + j.
// ---------------------------------------------------------------------------
template<int SRC16>
__global__ __launch_bounds__(256) void select_apply(
        const void* __restrict__ rawsrc,
        float* __restrict__ codes, float* __restrict__ mask,
        const int* __restrict__ kptr,
        const float* __restrict__ x, const float* __restrict__ W_enc,
        const float* __restrict__ b_enc, const float* __restrict__ tau,
        int* __restrict__ cnt_out, int* __restrict__ idx_out,
        float* __restrict__ val_out) {
    const int row = blockIdx.x;
    const int tid = threadIdx.x;
    const long base = (long)row * D_SAE;

    float c[8][8];
    if (SRC16) {
        const ushort* rh = (const ushort*)rawsrc;
        #pragma unroll
        for (int i = 0; i < 8; ++i) {
            uint4 u = *(const uint4*)(rh + base + i * 2048 + tid * 8);
            const unsigned* up = (const unsigned*)&u;
            #pragma unroll
            for (int q = 0; q < 4; ++q) {
                ushort b0 = (ushort)(up[q] & 0xFFFFu), b1 = (ushort)(up[q] >> 16);
                _Float16 h0, h1;
                *(ushort*)&h0 = b0; *(ushort*)&h1 = b1;
                c[i][2 * q]     = (float)h0;
                c[i][2 * q + 1] = (float)h1;
            }
        }
    } else {
        const float* rf = (const float*)rawsrc;
        #pragma unroll
        for (int i = 0; i < 8; ++i) {
            float4 v0 = *(const float4*)(rf + base + i * 2048 + tid * 8);
            float4 v1 = *(const float4*)(rf + base + i * 2048 + tid * 8 + 4);
            c[i][0] = v0.x; c[i][1] = v0.y; c[i][2] = v0.z; c[i][3] = v0.w;
            c[i][4] = v1.x; c[i][5] = v1.y; c[i][6] = v1.z; c[i][7] = v1.w;
        }
    }

    int K = kptr[0];
    if (K > D_SAE) K = D_SAE;

    __shared__ int    hist[1024];
    __shared__ int    scan[256];
    __shared__ int    wsum[4];
    __shared__ int    bidx[MAXB];
    __shared__ double exactv[MAXB];
    __shared__ int    selfl[MAXB];
    __shared__ double dsum[4];
    __shared__ int    sh_B, sh_nAB, sh_kpat;

    // --- 1a) histogram of f16-pattern top-10 bits (1024 buckets)
    #pragma unroll
    for (int q = 0; q < 4; ++q) hist[tid + q * 256] = 0;
    if (tid == 0) { sh_B = -1; sh_nAB = 0; }
    __syncthreads();
    #pragma unroll
    for (int i = 0; i < 8; ++i)
        #pragma unroll
        for (int j = 0; j < 8; ++j) {
            _Float16 h = (_Float16)c[i][j];
            ushort pat = *(ushort*)&h;
            if (pat) atomicAdd(&hist[pat >> 6], 1);
        }
    __syncthreads();

    // --- 1b) suffix scan over buckets (thread tid owns buckets 4t..4t+3)
    int s_loc = hist[4 * tid] + hist[4 * tid + 1] + hist[4 * tid + 2] + hist[4 * tid + 3];
    const int my = 255 - tid;
    scan[my] = s_loc;
    __syncthreads();
    #pragma unroll
    for (int off = 1; off < 256; off <<= 1) {
        int a = scan[my];
        int b = (my >= off) ? scan[my - off] : 0;
        __syncthreads();
        scan[my] = a + b;
        __syncthreads();
    }
    int I = scan[my];        // count of elements in buckets >= 4*tid
    int E = I - s_loc;       // count in buckets >= 4*(tid+1)
    if (I >= K && E < K) {   // exactly one thread (when enough positives)
        int cnt = E, b;
        for (b = 4 * tid + 3; b > 4 * tid; --b) {
            cnt += hist[b];
            if (cnt >= K) break;
        }
        if (cnt < K) { cnt += hist[4 * tid]; b = 4 * tid; }
        sh_B = b;
        sh_nAB = cnt - hist[b];    // elements strictly above bucket B
    }
    __syncthreads();
    const int B = sh_B, nAB = sh_nAB;

    // --- 1c) second pass within bucket B (low 6 bits)
    if (tid < 64) hist[tid] = 0;
    __syncthreads();
    if (B >= 0) {
        #pragma unroll
        for (int i = 0; i < 8; ++i)
            #pragma unroll
            for (int j = 0; j < 8; ++j) {
                _Float16 h = (_Float16)c[i][j];
                ushort pat = *(ushort*)&h;
                if (pat && (int)(pat >> 6) == B) atomicAdd(&hist[pat & 63], 1);
            }
    }
    __syncthreads();
    if (tid == 0) {
        int kpat = 0;
        if (B >= 0) {
            int cnt = nAB, l;
            for (l = 63; l >= 0; --l) {
                cnt += hist[l];
                if (cnt >= K) break;
            }
            if (l < 0) l = 0;
            kpat = (B << 6) | l;
        }
        sh_kpat = kpat;
    }
    __syncthreads();
    _Float16 kh; *(ushort*)&kh = (ushort)sh_kpat;
    const float kf = (float)kh;
    const float thr_hi = kf + DELTA;
    const float thr_lo = kf - DELTA;

    // --- 2) count above / collect band
    int cA = 0, cB2 = 0;
    #pragma unroll
    for (int i = 0; i < 8; ++i)
        #pragma unroll
        for (int j = 0; j < 8; ++j) {
            float cc = c[i][j];
            cA  += (cc > thr_hi);
            cB2 += (cc >= thr_lo) && (cc <= thr_hi);
        }
    {
        int a = cA;
        #pragma unroll
        for (int off = 32; off; off >>= 1) a += __shfl_xor(a, off, 64);
        if ((tid & 63) == 0) wsum[tid >> 6] = a;
    }
    __syncthreads();
    const int nA = wsum[0] + wsum[1] + wsum[2] + wsum[3];
    __syncthreads();

    scan[tid] = cB2;
    __syncthreads();
    #pragma unroll
    for (int off = 1; off < 256; off <<= 1) {
        int a = scan[tid];
        int b = (tid >= off) ? scan[tid - off] : 0;
        __syncthreads();
        scan[tid] = a + b;
        __syncthreads();
    }
    int posB = scan[tid] - cB2;
    int nb   = scan[255];
    if (nb > MAXB) nb = MAXB;

    {
        int p = posB;
        #pragma unroll
        for (int i = 0; i < 8; ++i)
            #pragma unroll
            for (int j = 0; j < 8; ++j) {
                float cc = c[i][j];
                if ((cc >= thr_lo) && (cc <= thr_hi)) {
                    if (p < MAXB) bidx[p] = i * 2048 + tid * 8 + j;
                    ++p;
                }
            }
    }
    __syncthreads();

    // --- 3) exact f64 pre for band candidates
    const float* xrow = x + (size_t)row * D_IN;
    for (int jj = 0; jj < nb; ++jj) {
        int s = bidx[jj];
        const float* wrow = W_enc + (size_t)s * D_IN;
        double a = 0.0;
        #pragma unroll
        for (int q = 0; q < 8; ++q)
            a += (double)xrow[tid * 8 + q] * (double)wrow[tid * 8 + q];
        #pragma unroll
        for (int off = 32; off; off >>= 1) a += __shfl_xor(a, off, 64);
        if ((tid & 63) == 0) dsum[tid >> 6] = a;
        __syncthreads();
        if (tid == 0)
            exactv[jj] = dsum[0] + dsum[1] + dsum[2] + dsum[3]
                         + (double)b_enc[s] - (double)tau[s];
        __syncthreads();
    }

    int m = K - nA;
    if (m > nb) m = nb;
    if (tid < nb) {
        double e = exactv[tid];
        int rank = 0;
        for (int l = 0; l < nb; ++l) rank += (exactv[l] > e);
        selfl[tid] = (rank < m) ? 1 : 0;
    }
    __syncthreads();

    // per-thread override bits: owner tid = (s>>3)&255, bit = (s>>11)*8 + (s&7)
    unsigned long long ov = 0ull;
    for (int jj = 0; jj < nb; ++jj) {
        int s = bidx[jj];
        if (((s >> 3) & 255) == tid && selfl[jj])
            ov |= 1ull << (((s >> 11) << 3) | (s & 7));
    }

    // --- 4) final keep predicate, compaction, writes
    int kc = 0;
    #pragma unroll
    for (int i = 0; i < 8; ++i)
        #pragma unroll
        for (int j = 0; j < 8; ++j) {
            float cc = c[i][j];
            bool sel = (cc > thr_hi) || ((ov >> (i * 8 + j)) & 1ull);
            kc += sel && (cc > 0.f);
        }
    __syncthreads();
    scan[tid] = kc;
    __syncthreads();
    #pragma unroll
    for (int off = 1; off < 256; off <<= 1) {
        int a = scan[tid];
        int b = (tid >= off) ? scan[tid - off] : 0;
        __syncthreads();
        scan[tid] = a + b;
        __syncthreads();
    }
    int pos   = scan[tid] - kc;
    int total = scan[255];

    #pragma unroll
    for (int i = 0; i < 8; ++i) {
        f32x4 cf0, cf1, mf0, mf1;
        #pragma unroll
        for (int j = 0; j < 8; ++j) {
            float cc = c[i][j];
            bool sel = (cc > thr_hi) || ((ov >> (i * 8 + j)) & 1ull);
            bool m_  = sel && (cc > 0.f);
            float cv = sel ? cc : 0.f;
            float mv = m_ ? 1.f : 0.f;
            if (j < 4) { cf0[j] = cv; mf0[j] = mv; }
            else       { cf1[j - 4] = cv; mf1[j - 4] = mv; }
            if (m_) {
                if (pos < CAP) {
                    idx_out[row * CAP + pos] = i * 2048 + tid * 8 + j;
                    val_out[row * CAP + pos] = cv;
                }
                ++pos;
            }
        }
        long o = base + i * 2048 + tid * 8;
        __builtin_nontemporal_store(cf0, (f32x4*)(codes + o));
        __builtin_nontemporal_store(cf1, (f32x4*)(codes + o + 4));
        __builtin_nontemporal_store(mf0, (f32x4*)(mask + o));
        __builtin_nontemporal_store(mf1, (f32x4*)(mask + o + 4));
    }
    if (tid == 0) cnt_out[row] = total < CAP ? total : CAP;
}

// ---------------------------------------------------------------------------
// K4: recon[b,:] = sum_j val_j * W_decT16[idx_j, :]   (f16 gather, f32 accum)
// Column-split: 2 blocks per row, 1024 cols each; per-element summation
// order identical -> deterministic.
// ---------------------------------------------------------------------------
__global__ __launch_bounds__(256) void recon_sparse(const _Float16* __restrict__ Wd16,
                                                    const int* __restrict__ cnt,
                                                    const int* __restrict__ idx,
                                                    const float* __restrict__ val,
                                                    float* __restrict__ recon) {
    const int row  = blockIdx.x >> 1;
    const int half = blockIdx.x & 1;
    const int tid  = threadIdx.x;
    __shared__ int   s_idx[CAP];
    __shared__ float s_val[CAP];
    const int n = cnt[row];
    for (int j = tid; j < n; j += 256) {
        s_idx[j] = idx[row * CAP + j];
        s_val[j] = val[row * CAP + j];
    }
    __syncthreads();

    const int colb = half * 1024 + tid * 4;
    float4 a = {0.f, 0.f, 0.f, 0.f};
    for (int j = 0; j < n; ++j) {
        float c = s_val[j];
        f16x4 w0 = *(const f16x4*)(Wd16 + (size_t)s_idx[j] * D_IN + colb);
        a.x = fmaf(c, (float)w0[0], a.x); a.y = fmaf(c, (float)w0[1], a.y);
        a.z = fmaf(c, (float)w0[2], a.z); a.w = fmaf(c, (float)w0[3], a.w);
    }
    *(float4*)(recon + (size_t)row * D_IN + colb) = a;
}

// ---------------------------------------------------------------------------
// Workspace:
//  f16-raw path (needs ~216.3 MB):
//   [0,64M)    w_f16 (phase A) / W_decT f16 (phase B, after select)
//   [64M,80M)  x_f16
//   [80M,208M) raw f16 codes
//   [208M,..)  cnt (16K), idx (4M), val (4M)
//  fallback (ws too small, ~88.3 MB): raw f32 lives in d_out codes region,
//   cnt/idx/val at 80M.
// ---------------------------------------------------------------------------
extern "C" void kernel_launch(void* const* d_in, const int* in_sizes, int n_in,
                              void* d_out, int out_size, void* d_ws, size_t ws_size,
                              hipStream_t stream) {
    const float* x     = (const float*)d_in[0];
    const float* W_enc = (const float*)d_in[1];
    const float* b_enc = (const float*)d_in[2];
    const float* tau   = (const float*)d_in[3];
    const float* W_dec = (const float*)d_in[4];
    const int*   kptr  = (const int*)d_in[5];

    float* recon = (float*)d_out;
    float* codes = recon + (size_t)BATCH * D_IN;
    float* maskp = codes + (size_t)BATCH * D_SAE;

    char* w = (char*)d_ws;
    const size_t OFF_X   = (size_t)D_SAE * D_IN * 2;             // 64M
    const size_t OFF_RAW = OFF_X + (size_t)BATCH * D_IN * 2;     // 80M
    const size_t RAWSZ   = (size_t)BATCH * D_SAE * 2;            // 128M
    const size_t TAILSZ  = 16384 + 2 * (size_t)BATCH * CAP * 4;  // cnt+idx+val
    const bool f16raw = ws_size >= OFF_RAW + RAWSZ + TAILSZ;

    const size_t OFF_CNT = f16raw ? (OFF_RAW + RAWSZ) : OFF_RAW;
    ushort*   w_f16  = (ushort*)w;
    ushort*   x_f16  = (ushort*)(w + OFF_X);
    _Float16* W_decT = (_Float16*)w;                             // phase B
    int*      cnt    = (int*)  (w + OFF_CNT);
    int*      idxl   = (int*)  (w + OFF_CNT + 16384);
    float*    vall   = (float*)(w + OFF_CNT + 16384 + (size_t)BATCH * CAP * 4);
    void*     raw    = f16raw ? (void*)(w + OFF_RAW) : (void*)codes;

    hipLaunchKernelGGL(to_f16, dim3(1024), dim3(256), 0, stream,
                       x, x_f16, BATCH * D_IN / 4);
    hipLaunchKernelGGL(to_f16, dim3(4096), dim3(256), 0, stream,
                       W_enc, w_f16, D_SAE * D_IN / 4);
    if (f16raw) {
        hipLaunchKernelGGL((gemm_enc_mfma<1>), dim3(BATCH / 256, D_SAE / 256), dim3(512), 0, stream,
                           x_f16, w_f16, b_enc, tau, raw);
        hipLaunchKernelGGL((select_apply<1>), dim3(BATCH), dim3(256), 0, stream,
                           raw, codes, maskp, kptr, x, W_enc, b_enc, tau, cnt, idxl, vall);
    } else {
        hipLaunchKernelGGL((gemm_enc_mfma<0>), dim3(BATCH / 256, D_SAE / 256), dim3(512), 0, stream,
                           x_f16, w_f16, b_enc, tau, raw);
        hipLaunchKernelGGL((select_apply<0>), dim3(BATCH), dim3(256), 0, stream,
                           raw, codes, maskp, kptr, x, W_enc, b_enc, tau, cnt, idxl, vall);
    }
    hipLaunchKernelGGL(transpose_wdec_f16, dim3(D_SAE / 64, D_IN / 64), dim3(256), 0, stream,
                       W_dec, W_decT);
    hipLaunchKernelGGL(recon_sparse, dim3(BATCH * 2), dim3(256), 0, stream,
                       W_decT, cnt, idxl, vall, recon);
}

// Round 15
// 692.128 us; speedup vs baseline: 1.3956x; 1.0115x over previous
//
#include <hip/hip_runtime.h>

#define D_IN   2048
#define D_SAE  16384
#define BATCH  4096
#define CAP    256      // max compacted nonzeros per row
#define MAXB   64       // max boundary-band candidates per row
#define DELTA  1e-2f    // band half-width; >= 2x (gemm f16 err + f16 storage err)

typedef __attribute__((ext_vector_type(8))) _Float16 f16x8;
typedef __attribute__((ext_vector_type(4))) _Float16 f16x4;
typedef __attribute__((ext_vector_type(4))) float f32x4;

// ---------------------------------------------------------------------------
// K0: convert f32 -> f16 (RN) for x and W_enc in one launch (r10-verified).
// ---------------------------------------------------------------------------
__global__ __launch_bounds__(256) void to_f16_2(const float* __restrict__ in1,
                                                ushort* __restrict__ out1, int n14,
                                                const float* __restrict__ in2,
                                                ushort* __restrict__ out2, int n24) {
    int i = blockIdx.x * blockDim.x + threadIdx.x;
    int stride = gridDim.x * blockDim.x;
    int total = n14 + n24;
    for (; i < total; i += stride) {
        const float4* src = (i < n14) ? ((const float4*)in1 + i)
                                      : ((const float4*)in2 + (i - n14));
        ushort4* dst = (i < n14) ? ((ushort4*)out1 + i)
                                 : ((ushort4*)out2 + (i - n14));
        float4 v = *src;
        ushort4 h;
        float*  vp = (float*)&v;
        ushort* hp = (ushort*)&h;
        #pragma unroll
        for (int j = 0; j < 4; ++j) {
            _Float16 f = (_Float16)vp[j];
            hp[j] = *(ushort*)&f;
        }
        *dst = h;
    }
}

// ---------------------------------------------------------------------------
// K1: raw[b][s] = relu( x·W_enc[s] + b_enc[s] - tau[s] ), f16 MFMA.
// r14-verified 9-slot ring, depth-5, counted vmcnt(4)/tile (perf-neutral vs
// r8 but passed; kept as current). Geometry/swizzle identical to r8.
// ---------------------------------------------------------------------------
__device__ __forceinline__ void async_copy16(const void* g, void* l) {
    __builtin_amdgcn_global_load_lds(
        (const __attribute__((address_space(1))) unsigned int*)g,
        (__attribute__((address_space(3))) unsigned int*)l, 16, 0, 0);
}

template<int F16OUT>
__global__ __launch_bounds__(512) void gemm_enc_mfma(
        const ushort* __restrict__ xh,    // x_f16 [4096][2048]
        const ushort* __restrict__ wh,    // w_f16 [16384][2048]
        const float* __restrict__ b_enc,
        const float* __restrict__ tau,
        void* __restrict__ rawout) {
    __shared__ ushort lds9[9][8192];   // 9 ring slots x 16 KB = 144 KB

    const int tid  = threadIdx.x;
    const int w    = tid >> 6;
    const int lane = tid & 63;
    const int wm   = w >> 2;
    const int wn   = w & 3;
    const int m0 = blockIdx.x * 256;
    const int s0 = blockIdx.y * 256;

    const int fr = lane & 15;
    const int fq = lane >> 4;

    const int srow0 = w * 8 + (lane >> 3);
    const int srow1 = 64 + srow0;
    const int sc0i  = (((lane & 7) - srow0) & 7) * 8;

    const ushort* panelA = xh + (size_t)m0 * 2048;
    const ushort* panelB = wh + (size_t)s0 * 2048;

    auto stage_unit = [&](int slot, int ab, int h, int koff) {
        const ushort* gp = (ab == 0) ? panelA : panelB;
        const ushort* g0 = gp + (size_t)(h * 128 + srow0) * 2048 + koff + sc0i;
        const ushort* g1 = gp + (size_t)(h * 128 + srow1) * 2048 + koff + sc0i;
        async_copy16(g0, &lds9[slot][w * 512]);
        async_copy16(g1, &lds9[slot][4096 + w * 512]);
    };

    int a_off[8][2], b_off[4][2];
    #pragma unroll
    for (int m = 0; m < 8; ++m) {
        int r = m * 16 + fr;
        #pragma unroll
        for (int kk = 0; kk < 2; ++kk)
            a_off[m][kk] = r * 64 + (((kk * 4 + fq) + r) & 7) * 8;
    }
    #pragma unroll
    for (int g = 0; g < 4; ++g) {
        int r = (wn & 1) * 64 + g * 16 + fr;
        #pragma unroll
        for (int kk = 0; kk < 2; ++kk)
            b_off[g][kk] = r * 64 + (((kk * 4 + fq) + r) & 7) * 8;
    }

    f32x4 acc[8][4] = {};

    stage_unit(0, 0, 0, 0);
    stage_unit(1, 1, 0, 0);
    stage_unit(2, 1, 1, 0);
    stage_unit(3, 0, 1, 0);
    stage_unit(4, 0, 0, 64);

    const int wmu = wm ? 3 : 0;
    const int wbu = 1 + (wn >> 1);

#define STG(P)                                                                 \
    do {                                                                       \
        int u_ = 4 * t + (P) + 5;                                              \
        if (u_ < 128) {                                                        \
            int ui_ = u_ & 3;                                                  \
            stage_unit(u_ % 9, (ui_ == 0 || ui_ == 3) ? 0 : 1,                 \
                       (ui_ >= 2) ? 1 : 0, (u_ >> 2) * 64);                    \
        }                                                                      \
    } while (0)

#define PHASE(QM, QN, P)                                                       \
    do {                                                                       \
        STG(P);                                                                \
        if ((P) == 0) {                                                        \
            if (t != 31) asm volatile("s_waitcnt vmcnt(4)" ::: "memory");      \
            else         asm volatile("s_waitcnt vmcnt(0)" ::: "memory");      \
        }                                                                      \
        asm volatile("s_barrier" ::: "memory");                                \
        f16x8 af[4][2], bf[2][2];                                              \
        _Pragma("unroll") for (int mm = 0; mm < 4; ++mm)                       \
            _Pragma("unroll") for (int kk = 0; kk < 2; ++kk)                   \
                af[mm][kk] = *(const f16x8*)&ldsA[a_off[(QM) * 4 + mm][kk]];   \
        _Pragma("unroll") for (int nn = 0; nn < 2; ++nn)                       \
            _Pragma("unroll") for (int kk = 0; kk < 2; ++kk)                   \
                bf[nn][kk] = *(const f16x8*)&ldsB[b_off[(QN) * 2 + nn][kk]];   \
        __builtin_amdgcn_s_setprio(1);                                         \
        _Pragma("unroll") for (int kk = 0; kk < 2; ++kk)                       \
            _Pragma("unroll") for (int mm = 0; mm < 4; ++mm)                   \
                _Pragma("unroll") for (int nn = 0; nn < 2; ++nn)               \
                    acc[(QM) * 4 + mm][(QN) * 2 + nn] =                        \
                        __builtin_amdgcn_mfma_f32_16x16x32_f16(                \
                            af[mm][kk], bf[nn][kk],                            \
                            acc[(QM) * 4 + mm][(QN) * 2 + nn], 0, 0, 0);       \
        __builtin_amdgcn_s_setprio(0);                                         \
        asm volatile("s_barrier" ::: "memory");                                \
    } while (0)

    for (int t = 0; t < 32; ++t) {
        const ushort* ldsA = &lds9[(4 * t + wmu) % 9][0];
        const ushort* ldsB = &lds9[(4 * t + wbu) % 9][0];
        PHASE(0, 0, 0);
        PHASE(0, 1, 1);
        PHASE(1, 0, 2);
        PHASE(1, 1, 3);
    }
#undef PHASE
#undef STG

    float bias[4];
    int col[4];
    #pragma unroll
    for (int n = 0; n < 4; ++n) {
        col[n] = s0 + wn * 64 + n * 16 + fr;
        bias[n] = b_enc[col[n]] - tau[col[n]];
    }
    #pragma unroll
    for (int m = 0; m < 8; ++m) {
        int rbase = m0 + wm * 128 + m * 16 + fq * 4;
        #pragma unroll
        for (int n = 0; n < 4; ++n) {
            #pragma unroll
            for (int r = 0; r < 4; ++r) {
                float v = fmaxf(acc[m][n][r] + bias[n], 0.f);
                size_t ofs = (size_t)(rbase + r) * D_SAE + col[n];
                if (F16OUT) {
                    _Float16 hv = (_Float16)v;
                    ((ushort*)rawout)[ofs] = *(ushort*)&hv;
                } else {
                    ((float*)rawout)[ofs] = v;
                }
            }
        }
    }
}

// ---------------------------------------------------------------------------
// K2: transpose W_dec (f32 [2048][16384]) -> W_decT (f16 [16384][2048])
// ---------------------------------------------------------------------------
__global__ __launch_bounds__(256) void transpose_wdec_f16(const float* __restrict__ W_dec,
                                                          _Float16* __restrict__ W_decT) {
    __shared__ float t[64][65];
    const int tid = threadIdx.x;
    const int x0 = blockIdx.x * 64;
    const int y0 = blockIdx.y * 64;
    const int tx = tid & 15;
    const int ty = tid >> 4;
    #pragma unroll
    for (int p = 0; p < 4; ++p) {
        float4 v = *(const float4*)&W_dec[(size_t)(y0 + p * 16 + ty) * D_SAE + x0 + tx * 4];
        t[p * 16 + ty][tx * 4 + 0] = v.x;
        t[p * 16 + ty][tx * 4 + 1] = v.y;
        t[p * 16 + ty][tx * 4 + 2] = v.z;
        t[p * 16 + ty][tx * 4 + 3] = v.w;
    }
    __syncthreads();
    #pragma unroll
    for (int p = 0; p < 4; ++p) {
        int s = p * 16 + ty;
        f16x4 o;
        #pragma unroll
        for (int q = 0; q < 4; ++q)
            o[q] = (_Float16)t[tx * 4 + q][s];
        *(f16x4*)&W_decT[(size_t)(x0 + s) * D_IN + y0 + tx * 4] = o;
    }
}

// ---------------------------------------------------------------------------
// Block-wide inclusive scan over 256 threads via wave shfl + cross-wave
// offsets. 2 barriers. Returns inclusive prefix; *pT = block total.
// ---------------------------------------------------------------------------
__device__ __forceinline__ int block_incl_scan(int v, int tid, int* wtot, int* pT) {
    const int lane = tid & 63, wid = tid >> 6;
    int s = v;
    #pragma unroll
    for (int off = 1; off < 64; off <<= 1) {
        int n = __shfl_up(s, off, 64);
        if (lane >= off) s += n;
    }
    if (lane == 63) wtot[wid] = s;
    __syncthreads();
    int pre = 0, T = 0;
    #pragma unroll
    for (int w2 = 0; w2 < 4; ++w2) {
        int t = wtot[w2];
        T += t;
        if (w2 < wid) pre += t;
    }
    __syncthreads();   // wtot reusable after this
    *pT = T;
    return s + pre;
}

// ---------------------------------------------------------------------------
// K3: exact rank-K select. Same math as round-8 (histogram kth localization
// + f64 band refinement, DELTA-exactness proof unchanged), re-plumbed:
//  - per-wave histograms hist4[4][1024] (atomic contention / 4)
//  - shfl-based block scans (2 barriers each vs 16); suffix count derived
//    as T - exclusive_prefix; band scan + above-count packed in one scan.
// s = i*2048 + tid*8 + j.
// ---------------------------------------------------------------------------
template<int SRC16>
__global__ __launch_bounds__(256) void select_apply(
        const void* __restrict__ rawsrc,
        float* __restrict__ codes, float* __restrict__ mask,
        const int* __restrict__ kptr,
        const float* __restrict__ x, const float* __restrict__ W_enc,
        const float* __restrict__ b_enc, const float* __restrict__ tau,
        int* __restrict__ cnt_out, int* __restrict__ idx_out,
        float* __restrict__ val_out) {
    const int row = blockIdx.x;
    const int tid = threadIdx.x;
    const int wid = tid >> 6;
    const long base = (long)row * D_SAE;

    float c[8][8];
    if (SRC16) {
        const ushort* rh = (const ushort*)rawsrc;
        #pragma unroll
        for (int i = 0; i < 8; ++i) {
            uint4 u = *(const uint4*)(rh + base + i * 2048 + tid * 8);
            const unsigned* up = (const unsigned*)&u;
            #pragma unroll
            for (int q = 0; q < 4; ++q) {
                ushort b0 = (ushort)(up[q] & 0xFFFFu), b1 = (ushort)(up[q] >> 16);
                _Float16 h0, h1;
                *(ushort*)&h0 = b0; *(ushort*)&h1 = b1;
                c[i][2 * q]     = (float)h0;
                c[i][2 * q + 1] = (float)h1;
            }
        }
    } else {
        const float* rf = (const float*)rawsrc;
        #pragma unroll
        for (int i = 0; i < 8; ++i) {
            float4 v0 = *(const float4*)(rf + base + i * 2048 + tid * 8);
            float4 v1 = *(const float4*)(rf + base + i * 2048 + tid * 8 + 4);
            c[i][0] = v0.x; c[i][1] = v0.y; c[i][2] = v0.z; c[i][3] = v0.w;
            c[i][4] = v1.x; c[i][5] = v1.y; c[i][6] = v1.z; c[i][7] = v1.w;
        }
    }

    int K = kptr[0];
    if (K > D_SAE) K = D_SAE;

    __shared__ int    hist4[4][1024];
    __shared__ int    hist1c[64];
    __shared__ int    wtot[4];
    __shared__ int    bidx[MAXB];
    __shared__ double exactv[MAXB];
    __shared__ int    selfl[MAXB];
    __shared__ double dsum[4];
    __shared__ int    sh_B, sh_nAB, sh_kpat;

    // --- 1a) per-wave histograms of f16-pattern top-10 bits
    #pragma unroll
    for (int q = 0; q < 16; ++q) ((int*)hist4)[tid + q * 256] = 0;
    if (tid < 64) hist1c[tid] = 0;
    if (tid == 0) { sh_B = -1; sh_nAB = 0; }
    __syncthreads();
    #pragma unroll
    for (int i = 0; i < 8; ++i)
        #pragma unroll
        for (int j = 0; j < 8; ++j) {
            _Float16 h = (_Float16)c[i][j];
            ushort pat = *(ushort*)&h;
            if (pat) atomicAdd(&hist4[wid][pat >> 6], 1);
        }
    __syncthreads();

    // --- 1b) merged counts for buckets 4*tid..4*tid+3; suffix via scan
    int mh[4];
    int s_loc = 0;
    #pragma unroll
    for (int q = 0; q < 4; ++q) {
        mh[q] = hist4[0][4 * tid + q] + hist4[1][4 * tid + q]
              + hist4[2][4 * tid + q] + hist4[3][4 * tid + q];
        s_loc += mh[q];
    }
    int T1;
    int incl1 = block_incl_scan(s_loc, tid, wtot, &T1);
    int I = T1 - (incl1 - s_loc);   // count in buckets >= 4*tid
    int E = I - s_loc;              // count in buckets >= 4*(tid+1)
    if (I >= K && E < K) {
        int cnt = E, b;
        for (b = 3; b > 0; --b) {
            cnt += mh[b];
            if (cnt >= K) break;
        }
        if (cnt < K) { cnt += mh[0]; b = 0; }
        sh_B = 4 * tid + b;
        sh_nAB = cnt - mh[b];
    }
    __syncthreads();
    const int B = sh_B, nAB = sh_nAB;

    // --- 1c) second pass within bucket B (low 6 bits)
    if (B >= 0) {
        #pragma unroll
        for (int i = 0; i < 8; ++i)
            #pragma unroll
            for (int j = 0; j < 8; ++j) {
                _Float16 h = (_Float16)c[i][j];
                ushort pat = *(ushort*)&h;
                if (pat && (int)(pat >> 6) == B) atomicAdd(&hist1c[pat & 63], 1);
            }
    }
    __syncthreads();
    if (tid == 0) {
        int kpat = 0;
        if (B >= 0) {
            int cnt = nAB, l;
            for (l = 63; l >= 0; --l) {
                cnt += hist1c[l];
                if (cnt >= K) break;
            }
            if (l < 0) l = 0;
            kpat = (B << 6) | l;
        }
        sh_kpat = kpat;
    }
    __syncthreads();
    _Float16 kh; *(ushort*)&kh = (ushort)sh_kpat;
    const float kf = (float)kh;
    const float thr_hi = kf + DELTA;
    const float thr_lo = kf - DELTA;

    // --- 2) above-count + band prefix in ONE packed scan
    int cA = 0, cB2 = 0;
    #pragma unroll
    for (int i = 0; i < 8; ++i)
        #pragma unroll
        for (int j = 0; j < 8; ++j) {
            float cc = c[i][j];
            cA  += (cc > thr_hi);
            cB2 += (cc >= thr_lo) && (cc <= thr_hi);
        }
    int pv = (cB2 << 16) | cA;      // both totals <= 16384: no carry
    int T2;
    int incl2 = block_incl_scan(pv, tid, wtot, &T2);
    int excl2 = incl2 - pv;
    const int nA = T2 & 0xFFFF;
    int posB = excl2 >> 16;
    int nb   = T2 >> 16;
    if (nb > MAXB) nb = MAXB;

    {
        int p = posB;
        #pragma unroll
        for (int i = 0; i < 8; ++i)
            #pragma unroll
            for (int j = 0; j < 8; ++j) {
                float cc = c[i][j];
                if ((cc >= thr_lo) && (cc <= thr_hi)) {
                    if (p < MAXB) bidx[p] = i * 2048 + tid * 8 + j;
                    ++p;
                }
            }
    }
    __syncthreads();

    // --- 3) exact f64 pre for band candidates
    const float* xrow = x + (size_t)row * D_IN;
    for (int jj = 0; jj < nb; ++jj) {
        int s = bidx[jj];
        const float* wrow = W_enc + (size_t)s * D_IN;
        double a = 0.0;
        #pragma unroll
        for (int q = 0; q < 8; ++q)
            a += (double)xrow[tid * 8 + q] * (double)wrow[tid * 8 + q];
        #pragma unroll
        for (int off = 32; off; off >>= 1) a += __shfl_xor(a, off, 64);
        if ((tid & 63) == 0) dsum[tid >> 6] = a;
        __syncthreads();
        if (tid == 0)
            exactv[jj] = dsum[0] + dsum[1] + dsum[2] + dsum[3]
                         + (double)b_enc[s] - (double)tau[s];
        __syncthreads();
    }

    int m = K - nA;
    if (m > nb) m = nb;
    if (tid < nb) {
        double e = exactv[tid];
        int rank = 0;
        for (int l = 0; l < nb; ++l) rank += (exactv[l] > e);
        selfl[tid] = (rank < m) ? 1 : 0;
    }
    __syncthreads();

    // per-thread override bits: owner tid = (s>>3)&255, bit = (s>>11)*8 + (s&7)
    unsigned long long ov = 0ull;
    for (int jj = 0; jj < nb; ++jj) {
        int s = bidx[jj];
        if (((s >> 3) & 255) == tid && selfl[jj])
            ov |= 1ull << (((s >> 11) << 3) | (s & 7));
    }

    // --- 4) final keep predicate, compaction scan, writes
    int kc = 0;
    #pragma unroll
    for (int i = 0; i < 8; ++i)
        #pragma unroll
        for (int j = 0; j < 8; ++j) {
            float cc = c[i][j];
            bool sel = (cc > thr_hi) || ((ov >> (i * 8 + j)) & 1ull);
            kc += sel && (cc > 0.f);
        }
    int T3;
    int incl3 = block_incl_scan(kc, tid, wtot, &T3);
    int pos   = incl3 - kc;
    int total = T3;

    #pragma unroll
    for (int i = 0; i < 8; ++i) {
        f32x4 cf0, cf1, mf0, mf1;
        #pragma unroll
        for (int j = 0; j < 8; ++j) {
            float cc = c[i][j];
            bool sel = (cc > thr_hi) || ((ov >> (i * 8 + j)) & 1ull);
            bool m_  = sel && (cc > 0.f);
            float cv = sel ? cc : 0.f;
            float mv = m_ ? 1.f : 0.f;
            if (j < 4) { cf0[j] = cv; mf0[j] = mv; }
            else       { cf1[j - 4] = cv; mf1[j - 4] = mv; }
            if (m_) {
                if (pos < CAP) {
                    idx_out[row * CAP + pos] = i * 2048 + tid * 8 + j;
                    val_out[row * CAP + pos] = cv;
                }
                ++pos;
            }
        }
        long o = base + i * 2048 + tid * 8;
        __builtin_nontemporal_store(cf0, (f32x4*)(codes + o));
        __builtin_nontemporal_store(cf1, (f32x4*)(codes + o + 4));
        __builtin_nontemporal_store(mf0, (f32x4*)(mask + o));
        __builtin_nontemporal_store(mf1, (f32x4*)(mask + o + 4));
    }
    if (tid == 0) cnt_out[row] = total < CAP ? total : CAP;
}

// ---------------------------------------------------------------------------
// K4: recon[b,:] = sum_j val_j * W_decT16[idx_j, :]   (f16 gather, f32 accum)
// Column-split: 2 blocks per row, 1024 cols each; summation order per
// output element unchanged -> deterministic.
// ---------------------------------------------------------------------------
__global__ __launch_bounds__(256) void recon_sparse(const _Float16* __restrict__ Wd16,
                                                    const int* __restrict__ cnt,
                                                    const int* __restrict__ idx,
                                                    const float* __restrict__ val,
                                                    float* __restrict__ recon) {
    const int row  = blockIdx.x >> 1;
    const int half = blockIdx.x & 1;
    const int tid  = threadIdx.x;
    __shared__ int   s_idx[CAP];
    __shared__ float s_val[CAP];
    const int n = cnt[row];
    for (int j = tid; j < n; j += 256) {
        s_idx[j] = idx[row * CAP + j];
        s_val[j] = val[row * CAP + j];
    }
    __syncthreads();

    const int colb = half * 1024 + tid * 4;
    float4 a = {0.f, 0.f, 0.f, 0.f};
    for (int j = 0; j < n; ++j) {
        float c = s_val[j];
        f16x4 w0 = *(const f16x4*)(Wd16 + (size_t)s_idx[j] * D_IN + colb);
        a.x = fmaf(c, (float)w0[0], a.x); a.y = fmaf(c, (float)w0[1], a.y);
        a.z = fmaf(c, (float)w0[2], a.z); a.w = fmaf(c, (float)w0[3], a.w);
    }
    *(float4*)(recon + (size_t)row * D_IN + colb) = a;
}

// ---------------------------------------------------------------------------
// Workspace:
//  f16-raw path (needs ~216.3 MB):
//   [0,64M)    w_f16 (phase A) / W_decT f16 (phase B, after select)
//   [64M,80M)  x_f16
//   [80M,208M) raw f16 codes
//   [208M,..)  cnt (16K), idx (4M), val (4M)
//  fallback (ws too small, ~88.3 MB): raw f32 lives in d_out codes region,
//   cnt/idx/val at 80M.
// ---------------------------------------------------------------------------
extern "C" void kernel_launch(void* const* d_in, const int* in_sizes, int n_in,
                              void* d_out, int out_size, void* d_ws, size_t ws_size,
                              hipStream_t stream) {
    const float* x     = (const float*)d_in[0];
    const float* W_enc = (const float*)d_in[1];
    const float* b_enc = (const float*)d_in[2];
    const float* tau   = (const float*)d_in[3];
    const float* W_dec = (const float*)d_in[4];
    const int*   kptr  = (const int*)d_in[5];

    float* recon = (float*)d_out;
    float* codes = recon + (size_t)BATCH * D_IN;
    float* maskp = codes + (size_t)BATCH * D_SAE;

    char* w = (char*)d_ws;
    const size_t OFF_X   = (size_t)D_SAE * D_IN * 2;             // 64M
    const size_t OFF_RAW = OFF_X + (size_t)BATCH * D_IN * 2;     // 80M
    const size_t RAWSZ   = (size_t)BATCH * D_SAE * 2;            // 128M
    const size_t TAILSZ  = 16384 + 2 * (size_t)BATCH * CAP * 4;  // cnt+idx+val
    const bool f16raw = ws_size >= OFF_RAW + RAWSZ + TAILSZ;

    const size_t OFF_CNT = f16raw ? (OFF_RAW + RAWSZ) : OFF_RAW;
    ushort*   w_f16  = (ushort*)w;
    ushort*   x_f16  = (ushort*)(w + OFF_X);
    _Float16* W_decT = (_Float16*)w;                             // phase B
    int*      cnt    = (int*)  (w + OFF_CNT);
    int*      idxl   = (int*)  (w + OFF_CNT + 16384);
    float*    vall   = (float*)(w + OFF_CNT + 16384 + (size_t)BATCH * CAP * 4);
    void*     raw    = f16raw ? (void*)(w + OFF_RAW) : (void*)codes;

    hipLaunchKernelGGL(to_f16_2, dim3(2560), dim3(256), 0, stream,
                       x, x_f16, BATCH * D_IN / 4,
                       W_enc, w_f16, D_SAE * D_IN / 4);
    if (f16raw) {
        hipLaunchKernelGGL((gemm_enc_mfma<1>), dim3(BATCH / 256, D_SAE / 256), dim3(512), 0, stream,
                           x_f16, w_f16, b_enc, tau, raw);
        hipLaunchKernelGGL((select_apply<1>), dim3(BATCH), dim3(256), 0, stream,
                           raw, codes, maskp, kptr, x, W_enc, b_enc, tau, cnt, idxl, vall);
    } else {
        hipLaunchKernelGGL((gemm_enc_mfma<0>), dim3(BATCH / 256, D_SAE / 256), dim3(512), 0, stream,
                           x_f16, w_f16, b_enc, tau, raw);
        hipLaunchKernelGGL((select_apply<0>), dim3(BATCH), dim3(256), 0, stream,
                           raw, codes, maskp, kptr, x, W_enc, b_enc, tau, cnt, idxl, vall);
    }
    hipLaunchKernelGGL(transpose_wdec_f16, dim3(D_SAE / 64, D_IN / 64), dim3(256), 0, stream,
                       W_dec, W_decT);
    hipLaunchKernelGGL(recon_sparse, dim3(BATCH * 2), dim3(256), 0, stream,
                       W_decT, cnt, idxl, vall, recon);
}

// Round 16
// 653.593 us; speedup vs baseline: 1.4778x; 1.0590x over previous
//
#include <hip/hip_runtime.h>

#define D_IN   2048
#define D_SAE  16384
#define BATCH  4096
#define CAP    256      // max compacted nonzeros per row
#define MAXB   64       // max boundary-band candidates per row
#define DELTA  1e-2f    // band half-width; >= 2x (gemm f16 err + f16 storage err)

typedef __attribute__((ext_vector_type(8))) _Float16 f16x8;
typedef __attribute__((ext_vector_type(4))) _Float16 f16x4;
typedef __attribute__((ext_vector_type(4))) float f32x4;

// ---------------------------------------------------------------------------
// K0: convert f32 -> f16 (RN) for x and W_enc in one launch.
// ---------------------------------------------------------------------------
__global__ __launch_bounds__(256) void to_f16_2(const float* __restrict__ in1,
                                                ushort* __restrict__ out1, int n14,
                                                const float* __restrict__ in2,
                                                ushort* __restrict__ out2, int n24) {
    int i = blockIdx.x * blockDim.x + threadIdx.x;
    int stride = gridDim.x * blockDim.x;
    int total = n14 + n24;
    for (; i < total; i += stride) {
        const float4* src = (i < n14) ? ((const float4*)in1 + i)
                                      : ((const float4*)in2 + (i - n14));
        ushort4* dst = (i < n14) ? ((ushort4*)out1 + i)
                                 : ((ushort4*)out2 + (i - n14));
        float4 v = *src;
        ushort4 h;
        float*  vp = (float*)&v;
        ushort* hp = (ushort*)&h;
        #pragma unroll
        for (int j = 0; j < 4; ++j) {
            _Float16 f = (_Float16)vp[j];
            hp[j] = *(ushort*)&f;
        }
        *dst = h;
    }
}

// ---------------------------------------------------------------------------
// K1: raw[b][s] = relu( x·W_enc[s] + b_enc[s] - tau[s] ), f16 MFMA.
// r14-verified 9-slot ring, depth-5, counted vmcnt(4)/tile.
// ---------------------------------------------------------------------------
__device__ __forceinline__ void async_copy16(const void* g, void* l) {
    __builtin_amdgcn_global_load_lds(
        (const __attribute__((address_space(1))) unsigned int*)g,
        (__attribute__((address_space(3))) unsigned int*)l, 16, 0, 0);
}

template<int F16OUT>
__global__ __launch_bounds__(512) void gemm_enc_mfma(
        const ushort* __restrict__ xh,    // x_f16 [4096][2048]
        const ushort* __restrict__ wh,    // w_f16 [16384][2048]
        const float* __restrict__ b_enc,
        const float* __restrict__ tau,
        void* __restrict__ rawout) {
    __shared__ ushort lds9[9][8192];   // 9 ring slots x 16 KB = 144 KB

    const int tid  = threadIdx.x;
    const int w    = tid >> 6;
    const int lane = tid & 63;
    const int wm   = w >> 2;
    const int wn   = w & 3;
    const int m0 = blockIdx.x * 256;
    const int s0 = blockIdx.y * 256;

    const int fr = lane & 15;
    const int fq = lane >> 4;

    const int srow0 = w * 8 + (lane >> 3);
    const int srow1 = 64 + srow0;
    const int sc0i  = (((lane & 7) - srow0) & 7) * 8;

    const ushort* panelA = xh + (size_t)m0 * 2048;
    const ushort* panelB = wh + (size_t)s0 * 2048;

    auto stage_unit = [&](int slot, int ab, int h, int koff) {
        const ushort* gp = (ab == 0) ? panelA : panelB;
        const ushort* g0 = gp + (size_t)(h * 128 + srow0) * 2048 + koff + sc0i;
        const ushort* g1 = gp + (size_t)(h * 128 + srow1) * 2048 + koff + sc0i;
        async_copy16(g0, &lds9[slot][w * 512]);
        async_copy16(g1, &lds9[slot][4096 + w * 512]);
    };

    int a_off[8][2], b_off[4][2];
    #pragma unroll
    for (int m = 0; m < 8; ++m) {
        int r = m * 16 + fr;
        #pragma unroll
        for (int kk = 0; kk < 2; ++kk)
            a_off[m][kk] = r * 64 + (((kk * 4 + fq) + r) & 7) * 8;
    }
    #pragma unroll
    for (int g = 0; g < 4; ++g) {
        int r = (wn & 1) * 64 + g * 16 + fr;
        #pragma unroll
        for (int kk = 0; kk < 2; ++kk)
            b_off[g][kk] = r * 64 + (((kk * 4 + fq) + r) & 7) * 8;
    }

    f32x4 acc[8][4] = {};

    stage_unit(0, 0, 0, 0);
    stage_unit(1, 1, 0, 0);
    stage_unit(2, 1, 1, 0);
    stage_unit(3, 0, 1, 0);
    stage_unit(4, 0, 0, 64);

    const int wmu = wm ? 3 : 0;
    const int wbu = 1 + (wn >> 1);

#define STG(P)                                                                 \
    do {                                                                       \
        int u_ = 4 * t + (P) + 5;                                              \
        if (u_ < 128) {                                                        \
            int ui_ = u_ & 3;                                                  \
            stage_unit(u_ % 9, (ui_ == 0 || ui_ == 3) ? 0 : 1,                 \
                       (ui_ >= 2) ? 1 : 0, (u_ >> 2) * 64);                    \
        }                                                                      \
    } while (0)

#define PHASE(QM, QN, P)                                                       \
    do {                                                                       \
        STG(P);                                                                \
        if ((P) == 0) {                                                        \
            if (t != 31) asm volatile("s_waitcnt vmcnt(4)" ::: "memory");      \
            else         asm volatile("s_waitcnt vmcnt(0)" ::: "memory");      \
        }                                                                      \
        asm volatile("s_barrier" ::: "memory");                                \
        f16x8 af[4][2], bf[2][2];                                              \
        _Pragma("unroll") for (int mm = 0; mm < 4; ++mm)                       \
            _Pragma("unroll") for (int kk = 0; kk < 2; ++kk)                   \
                af[mm][kk] = *(const f16x8*)&ldsA[a_off[(QM) * 4 + mm][kk]];   \
        _Pragma("unroll") for (int nn = 0; nn < 2; ++nn)                       \
            _Pragma("unroll") for (int kk = 0; kk < 2; ++kk)                   \
                bf[nn][kk] = *(const f16x8*)&ldsB[b_off[(QN) * 2 + nn][kk]];   \
        __builtin_amdgcn_s_setprio(1);                                         \
        _Pragma("unroll") for (int kk = 0; kk < 2; ++kk)                       \
            _Pragma("unroll") for (int mm = 0; mm < 4; ++mm)                   \
                _Pragma("unroll") for (int nn = 0; nn < 2; ++nn)               \
                    acc[(QM) * 4 + mm][(QN) * 2 + nn] =                        \
                        __builtin_amdgcn_mfma_f32_16x16x32_f16(                \
                            af[mm][kk], bf[nn][kk],                            \
                            acc[(QM) * 4 + mm][(QN) * 2 + nn], 0, 0, 0);       \
        __builtin_amdgcn_s_setprio(0);                                         \
        asm volatile("s_barrier" ::: "memory");                                \
    } while (0)

    for (int t = 0; t < 32; ++t) {
        const ushort* ldsA = &lds9[(4 * t + wmu) % 9][0];
        const ushort* ldsB = &lds9[(4 * t + wbu) % 9][0];
        PHASE(0, 0, 0);
        PHASE(0, 1, 1);
        PHASE(1, 0, 2);
        PHASE(1, 1, 3);
    }
#undef PHASE
#undef STG

    float bias[4];
    int col[4];
    #pragma unroll
    for (int n = 0; n < 4; ++n) {
        col[n] = s0 + wn * 64 + n * 16 + fr;
        bias[n] = b_enc[col[n]] - tau[col[n]];
    }
    #pragma unroll
    for (int m = 0; m < 8; ++m) {
        int rbase = m0 + wm * 128 + m * 16 + fq * 4;
        #pragma unroll
        for (int n = 0; n < 4; ++n) {
            #pragma unroll
            for (int r = 0; r < 4; ++r) {
                float v = fmaxf(acc[m][n][r] + bias[n], 0.f);
                size_t ofs = (size_t)(rbase + r) * D_SAE + col[n];
                if (F16OUT) {
                    _Float16 hv = (_Float16)v;
                    ((ushort*)rawout)[ofs] = *(ushort*)&hv;
                } else {
                    ((float*)rawout)[ofs] = v;
                }
            }
        }
    }
}

// ---------------------------------------------------------------------------
// K2: transpose W_dec (f32 [2048][16384]) -> W_decT (f16 [16384][2048])
// ---------------------------------------------------------------------------
__global__ __launch_bounds__(256) void transpose_wdec_f16(const float* __restrict__ W_dec,
                                                          _Float16* __restrict__ W_decT) {
    __shared__ float t[64][65];
    const int tid = threadIdx.x;
    const int x0 = blockIdx.x * 64;
    const int y0 = blockIdx.y * 64;
    const int tx = tid & 15;
    const int ty = tid >> 4;
    #pragma unroll
    for (int p = 0; p < 4; ++p) {
        float4 v = *(const float4*)&W_dec[(size_t)(y0 + p * 16 + ty) * D_SAE + x0 + tx * 4];
        t[p * 16 + ty][tx * 4 + 0] = v.x;
        t[p * 16 + ty][tx * 4 + 1] = v.y;
        t[p * 16 + ty][tx * 4 + 2] = v.z;
        t[p * 16 + ty][tx * 4 + 3] = v.w;
    }
    __syncthreads();
    #pragma unroll
    for (int p = 0; p < 4; ++p) {
        int s = p * 16 + ty;
        f16x4 o;
        #pragma unroll
        for (int q = 0; q < 4; ++q)
            o[q] = (_Float16)t[tx * 4 + q][s];
        *(f16x4*)&W_decT[(size_t)(x0 + s) * D_IN + y0 + tx * 4] = o;
    }
}

// ---------------------------------------------------------------------------
// Block-wide inclusive scan over 256 threads via wave shfl + cross-wave
// offsets. 2 barriers. Returns inclusive prefix; *pT = block total.
// ---------------------------------------------------------------------------
__device__ __forceinline__ int block_incl_scan(int v, int tid, int* wtot, int* pT) {
    const int lane = tid & 63, wid = tid >> 6;
    int s = v;
    #pragma unroll
    for (int off = 1; off < 64; off <<= 1) {
        int n = __shfl_up(s, off, 64);
        if (lane >= off) s += n;
    }
    if (lane == 63) wtot[wid] = s;
    __syncthreads();
    int pre = 0, T = 0;
    #pragma unroll
    for (int w2 = 0; w2 < 4; ++w2) {
        int t = wtot[w2];
        T += t;
        if (w2 < wid) pre += t;
    }
    __syncthreads();
    *pT = T;
    return s + pre;
}

// ---------------------------------------------------------------------------
// K3: FUSED select + recon. Select phase identical math to r15 (histogram
// kth localization + f64 band refinement; DELTA-exactness proof unchanged);
// compacted (idx,val) list goes to LDS (no HBM round trip), then the same
// block gathers W_decT rows and writes recon. Overlaps select's HBM-write-
// bound phase with recon's L3-read-bound phase across in-flight blocks.
// Compaction order (tid-major, then i,j) identical to r15 -> same summation
// order -> bit-identical recon.
// ---------------------------------------------------------------------------
template<int SRC16>
__global__ __launch_bounds__(256) void select_recon(
        const void* __restrict__ rawsrc,
        float* __restrict__ codes, float* __restrict__ mask,
        const int* __restrict__ kptr,
        const float* __restrict__ x, const float* __restrict__ W_enc,
        const float* __restrict__ b_enc, const float* __restrict__ tau,
        const _Float16* __restrict__ Wd16,
        float* __restrict__ recon) {
    const int row = blockIdx.x;
    const int tid = threadIdx.x;
    const int wid = tid >> 6;
    const long base = (long)row * D_SAE;

    float c[8][8];
    if (SRC16) {
        const ushort* rh = (const ushort*)rawsrc;
        #pragma unroll
        for (int i = 0; i < 8; ++i) {
            uint4 u = *(const uint4*)(rh + base + i * 2048 + tid * 8);
            const unsigned* up = (const unsigned*)&u;
            #pragma unroll
            for (int q = 0; q < 4; ++q) {
                ushort b0 = (ushort)(up[q] & 0xFFFFu), b1 = (ushort)(up[q] >> 16);
                _Float16 h0, h1;
                *(ushort*)&h0 = b0; *(ushort*)&h1 = b1;
                c[i][2 * q]     = (float)h0;
                c[i][2 * q + 1] = (float)h1;
            }
        }
    } else {
        const float* rf = (const float*)rawsrc;
        #pragma unroll
        for (int i = 0; i < 8; ++i) {
            float4 v0 = *(const float4*)(rf + base + i * 2048 + tid * 8);
            float4 v1 = *(const float4*)(rf + base + i * 2048 + tid * 8 + 4);
            c[i][0] = v0.x; c[i][1] = v0.y; c[i][2] = v0.z; c[i][3] = v0.w;
            c[i][4] = v1.x; c[i][5] = v1.y; c[i][6] = v1.z; c[i][7] = v1.w;
        }
    }

    int K = kptr[0];
    if (K > D_SAE) K = D_SAE;

    __shared__ int    hist4[4][1024];
    __shared__ int    hist1c[64];
    __shared__ int    wtot[4];
    __shared__ int    bidx[MAXB];
    __shared__ double exactv[MAXB];
    __shared__ int    selfl[MAXB];
    __shared__ double dsum[4];
    __shared__ int    sh_B, sh_nAB, sh_kpat;
    __shared__ int    s_idx[CAP];
    __shared__ float  s_val[CAP];

    // --- 1a) per-wave histograms of f16-pattern top-10 bits
    #pragma unroll
    for (int q = 0; q < 16; ++q) ((int*)hist4)[tid + q * 256] = 0;
    if (tid < 64) hist1c[tid] = 0;
    if (tid == 0) { sh_B = -1; sh_nAB = 0; }
    __syncthreads();
    #pragma unroll
    for (int i = 0; i < 8; ++i)
        #pragma unroll
        for (int j = 0; j < 8; ++j) {
            _Float16 h = (_Float16)c[i][j];
            ushort pat = *(ushort*)&h;
            if (pat) atomicAdd(&hist4[wid][pat >> 6], 1);
        }
    __syncthreads();

    // --- 1b) merged counts; kth bucket via scan
    int mh[4];
    int s_loc = 0;
    #pragma unroll
    for (int q = 0; q < 4; ++q) {
        mh[q] = hist4[0][4 * tid + q] + hist4[1][4 * tid + q]
              + hist4[2][4 * tid + q] + hist4[3][4 * tid + q];
        s_loc += mh[q];
    }
    int T1;
    int incl1 = block_incl_scan(s_loc, tid, wtot, &T1);
    int I = T1 - (incl1 - s_loc);
    int E = I - s_loc;
    if (I >= K && E < K) {
        int cnt = E, b;
        for (b = 3; b > 0; --b) {
            cnt += mh[b];
            if (cnt >= K) break;
        }
        if (cnt < K) { cnt += mh[0]; b = 0; }
        sh_B = 4 * tid + b;
        sh_nAB = cnt - mh[b];
    }
    __syncthreads();
    const int B = sh_B, nAB = sh_nAB;

    // --- 1c) second pass within bucket B
    if (B >= 0) {
        #pragma unroll
        for (int i = 0; i < 8; ++i)
            #pragma unroll
            for (int j = 0; j < 8; ++j) {
                _Float16 h = (_Float16)c[i][j];
                ushort pat = *(ushort*)&h;
                if (pat && (int)(pat >> 6) == B) atomicAdd(&hist1c[pat & 63], 1);
            }
    }
    __syncthreads();
    if (tid == 0) {
        int kpat = 0;
        if (B >= 0) {
            int cnt = nAB, l;
            for (l = 63; l >= 0; --l) {
                cnt += hist1c[l];
                if (cnt >= K) break;
            }
            if (l < 0) l = 0;
            kpat = (B << 6) | l;
        }
        sh_kpat = kpat;
    }
    __syncthreads();
    _Float16 kh; *(ushort*)&kh = (ushort)sh_kpat;
    const float kf = (float)kh;
    const float thr_hi = kf + DELTA;
    const float thr_lo = kf - DELTA;

    // --- 2) above-count + band prefix in one packed scan
    int cA = 0, cB2 = 0;
    #pragma unroll
    for (int i = 0; i < 8; ++i)
        #pragma unroll
        for (int j = 0; j < 8; ++j) {
            float cc = c[i][j];
            cA  += (cc > thr_hi);
            cB2 += (cc >= thr_lo) && (cc <= thr_hi);
        }
    int pv = (cB2 << 16) | cA;
    int T2;
    int incl2 = block_incl_scan(pv, tid, wtot, &T2);
    int excl2 = incl2 - pv;
    const int nA = T2 & 0xFFFF;
    int posB = excl2 >> 16;
    int nb   = T2 >> 16;
    if (nb > MAXB) nb = MAXB;

    {
        int p = posB;
        #pragma unroll
        for (int i = 0; i < 8; ++i)
            #pragma unroll
            for (int j = 0; j < 8; ++j) {
                float cc = c[i][j];
                if ((cc >= thr_lo) && (cc <= thr_hi)) {
                    if (p < MAXB) bidx[p] = i * 2048 + tid * 8 + j;
                    ++p;
                }
            }
    }
    __syncthreads();

    // --- 3) exact f64 pre for band candidates
    const float* xrow = x + (size_t)row * D_IN;
    for (int jj = 0; jj < nb; ++jj) {
        int s = bidx[jj];
        const float* wrow = W_enc + (size_t)s * D_IN;
        double a = 0.0;
        #pragma unroll
        for (int q = 0; q < 8; ++q)
            a += (double)xrow[tid * 8 + q] * (double)wrow[tid * 8 + q];
        #pragma unroll
        for (int off = 32; off; off >>= 1) a += __shfl_xor(a, off, 64);
        if ((tid & 63) == 0) dsum[tid >> 6] = a;
        __syncthreads();
        if (tid == 0)
            exactv[jj] = dsum[0] + dsum[1] + dsum[2] + dsum[3]
                         + (double)b_enc[s] - (double)tau[s];
        __syncthreads();
    }

    int m = K - nA;
    if (m > nb) m = nb;
    if (tid < nb) {
        double e = exactv[tid];
        int rank = 0;
        for (int l = 0; l < nb; ++l) rank += (exactv[l] > e);
        selfl[tid] = (rank < m) ? 1 : 0;
    }
    __syncthreads();

    unsigned long long ov = 0ull;
    for (int jj = 0; jj < nb; ++jj) {
        int s = bidx[jj];
        if (((s >> 3) & 255) == tid && selfl[jj])
            ov |= 1ull << (((s >> 11) << 3) | (s & 7));
    }

    // --- 4) final keep predicate, compaction scan, dense writes + LDS list
    int kc = 0;
    #pragma unroll
    for (int i = 0; i < 8; ++i)
        #pragma unroll
        for (int j = 0; j < 8; ++j) {
            float cc = c[i][j];
            bool sel = (cc > thr_hi) || ((ov >> (i * 8 + j)) & 1ull);
            kc += sel && (cc > 0.f);
        }
    int T3;
    int incl3 = block_incl_scan(kc, tid, wtot, &T3);
    int pos = incl3 - kc;

    #pragma unroll
    for (int i = 0; i < 8; ++i) {
        f32x4 cf0, cf1, mf0, mf1;
        #pragma unroll
        for (int j = 0; j < 8; ++j) {
            float cc = c[i][j];
            bool sel = (cc > thr_hi) || ((ov >> (i * 8 + j)) & 1ull);
            bool m_  = sel && (cc > 0.f);
            float cv = sel ? cc : 0.f;
            float mv = m_ ? 1.f : 0.f;
            if (j < 4) { cf0[j] = cv; mf0[j] = mv; }
            else       { cf1[j - 4] = cv; mf1[j - 4] = mv; }
            if (m_) {
                if (pos < CAP) {
                    s_idx[pos] = i * 2048 + tid * 8 + j;
                    s_val[pos] = cv;
                }
                ++pos;
            }
        }
        long o = base + i * 2048 + tid * 8;
        __builtin_nontemporal_store(cf0, (f32x4*)(codes + o));
        __builtin_nontemporal_store(cf1, (f32x4*)(codes + o + 4));
        __builtin_nontemporal_store(mf0, (f32x4*)(mask + o));
        __builtin_nontemporal_store(mf1, (f32x4*)(mask + o + 4));
    }
    __syncthreads();

    // --- 5) recon phase (r8-verified gather loop; list is in LDS)
    const int n = (T3 < CAP) ? T3 : CAP;
    float4 a0 = {0.f, 0.f, 0.f, 0.f};
    float4 a1 = {0.f, 0.f, 0.f, 0.f};
    for (int j = 0; j < n; ++j) {
        float cv = s_val[j];
        const _Float16* wp = Wd16 + (size_t)s_idx[j] * D_IN;
        f16x4 w0 = *(const f16x4*)(wp + tid * 4);
        f16x4 w1 = *(const f16x4*)(wp + 1024 + tid * 4);
        a0.x = fmaf(cv, (float)w0[0], a0.x); a0.y = fmaf(cv, (float)w0[1], a0.y);
        a0.z = fmaf(cv, (float)w0[2], a0.z); a0.w = fmaf(cv, (float)w0[3], a0.w);
        a1.x = fmaf(cv, (float)w1[0], a1.x); a1.y = fmaf(cv, (float)w1[1], a1.y);
        a1.z = fmaf(cv, (float)w1[2], a1.z); a1.w = fmaf(cv, (float)w1[3], a1.w);
    }
    float* out = recon + (size_t)row * D_IN;
    *(float4*)(out + tid * 4)        = a0;
    *(float4*)(out + 1024 + tid * 4) = a1;
}

// ---------------------------------------------------------------------------
// Workspace:
//  f16-raw path (needs ~208 MB):
//   [0,64M)    w_f16 (phase A) / W_decT f16 (phase B — transpose runs AFTER
//              gemm, before select_recon; gemm is the last w_f16 reader)
//   [64M,80M)  x_f16
//   [80M,208M) raw f16 codes
//  fallback (ws too small): raw f32 lives in d_out codes region.
// ---------------------------------------------------------------------------
extern "C" void kernel_launch(void* const* d_in, const int* in_sizes, int n_in,
                              void* d_out, int out_size, void* d_ws, size_t ws_size,
                              hipStream_t stream) {
    const float* x     = (const float*)d_in[0];
    const float* W_enc = (const float*)d_in[1];
    const float* b_enc = (const float*)d_in[2];
    const float* tau   = (const float*)d_in[3];
    const float* W_dec = (const float*)d_in[4];
    const int*   kptr  = (const int*)d_in[5];

    float* recon = (float*)d_out;
    float* codes = recon + (size_t)BATCH * D_IN;
    float* maskp = codes + (size_t)BATCH * D_SAE;

    char* w = (char*)d_ws;
    const size_t OFF_X   = (size_t)D_SAE * D_IN * 2;             // 64M
    const size_t OFF_RAW = OFF_X + (size_t)BATCH * D_IN * 2;     // 80M
    const size_t RAWSZ   = (size_t)BATCH * D_SAE * 2;            // 128M
    const bool f16raw = ws_size >= OFF_RAW + RAWSZ;

    ushort*   w_f16  = (ushort*)w;
    ushort*   x_f16  = (ushort*)(w + OFF_X);
    _Float16* W_decT = (_Float16*)w;                             // phase B
    void*     raw    = f16raw ? (void*)(w + OFF_RAW) : (void*)codes;

    hipLaunchKernelGGL(to_f16_2, dim3(2560), dim3(256), 0, stream,
                       x, x_f16, BATCH * D_IN / 4,
                       W_enc, w_f16, D_SAE * D_IN / 4);
    if (f16raw) {
        hipLaunchKernelGGL((gemm_enc_mfma<1>), dim3(BATCH / 256, D_SAE / 256), dim3(512), 0, stream,
                           x_f16, w_f16, b_enc, tau, raw);
        // transpose AFTER gemm (gemm is the last w_f16 reader; W_decT
        // overwrites that region) and BEFORE the fused select+recon.
        hipLaunchKernelGGL(transpose_wdec_f16, dim3(D_SAE / 64, D_IN / 64), dim3(256), 0, stream,
                           W_dec, W_decT);
        hipLaunchKernelGGL((select_recon<1>), dim3(BATCH), dim3(256), 0, stream,
                           raw, codes, maskp, kptr, x, W_enc, b_enc, tau, W_decT, recon);
    } else {
        hipLaunchKernelGGL((gemm_enc_mfma<0>), dim3(BATCH / 256, D_SAE / 256), dim3(512), 0, stream,
                           x_f16, w_f16, b_enc, tau, raw);
        hipLaunchKernelGGL(transpose_wdec_f16, dim3(D_SAE / 64, D_IN / 64), dim3(256), 0, stream,
                           W_dec, W_decT);
        hipLaunchKernelGGL((select_recon<0>), dim3(BATCH), dim3(256), 0, stream,
                           raw, codes, maskp, kptr, x, W_enc, b_enc, tau, W_decT, recon);
    }
}